// Round 1
// baseline (1357.640 us; speedup 1.0000x reference)
//
#include <hip/hip_runtime.h>
#include <hip/hip_fp16.h>

#define NROWS 32768
#define DIMS 256
#define KCODES 8192
#define MARGIN 0.15f

typedef _Float16 half8 __attribute__((ext_vector_type(8)));
typedef float f32x4 __attribute__((ext_vector_type(4)));

// ---------------------------------------------------------------------------
// K1: codebook squared norms; zero worklist counter and loss cell.
// ---------------------------------------------------------------------------
__global__ void k_cnorm(const float* __restrict__ cb, float* __restrict__ cnorm,
                        int* __restrict__ wcount, float* __restrict__ loss_cell) {
  const int lane = threadIdx.x & 63;
  const int code = blockIdx.x * 4 + (threadIdx.x >> 6);
  const float4 v = *((const float4*)(cb + code * DIMS) + lane);
  float s = v.x * v.x + v.y * v.y + v.z * v.z + v.w * v.w;
#pragma unroll
  for (int m = 1; m < 64; m <<= 1) s += __shfl_xor(s, m);
  if (lane == 0) cnorm[code] = s;
  if (blockIdx.x == 0 && threadIdx.x == 0) { *wcount = 0; *loss_cell = 0.0f; }
}

// ---------------------------------------------------------------------------
// K2: f16 MFMA distance GEMM with per-row approximate top-2 tracking.
// Block = 512 thr (8 waves), each wave owns 32 rows; block covers 4096 codes
// (half of K). d_approx = ||c||^2 - 2 x.c  (||x||^2 dropped: per-row const).
// ---------------------------------------------------------------------------
__launch_bounds__(512, 2)
__global__ void k_gemm(const float* __restrict__ x, const float* __restrict__ cb,
                       const float* __restrict__ cnorm,
                       float* __restrict__ d1h, float* __restrict__ d2h,
                       int* __restrict__ idxh) {
  __shared__ _Float16 clds[128][40];  // 128 codes x 32 dims, padded to 40 halves
  const int tid = threadIdx.x;
  const int lane = tid & 63;
  const int w = tid >> 6;
  const int l15 = lane & 15;
  const int lh = lane >> 4;
  const int rowblk = (int)blockIdx.x >> 1;
  const int half = (int)blockIdx.x & 1;
  const int row0 = rowblk * 256 + w * 32;

  // Preload x rows as A fragments (f16, RTN), resident for whole kernel.
  half8 a[2][8];
#pragma unroll
  for (int m = 0; m < 2; ++m) {
#pragma unroll
    for (int kf = 0; kf < 8; ++kf) {
      const float* s = x + (row0 + m * 16 + l15) * DIMS + kf * 32 + lh * 8;
      const float4 v0 = *(const float4*)s;
      const float4 v1 = *(const float4*)(s + 4);
      half8 h;
      h[0] = (_Float16)v0.x; h[1] = (_Float16)v0.y;
      h[2] = (_Float16)v0.z; h[3] = (_Float16)v0.w;
      h[4] = (_Float16)v1.x; h[5] = (_Float16)v1.y;
      h[6] = (_Float16)v1.z; h[7] = (_Float16)v1.w;
      a[m][kf] = h;
    }
  }

  // Running per-row-slot top-2 (slots: m in {0,1}, j in {0..3}).
  float rd1[2][4], rd2[2][4];
  int ridx[2][4];
#pragma unroll
  for (int m = 0; m < 2; ++m)
#pragma unroll
    for (int j = 0; j < 4; ++j) { rd1[m][j] = 3.0e38f; rd2[m][j] = 3.0e38f; ridx[m][j] = 0; }

  const int stg_code = tid >> 2;
  const int stg_seg = tid & 3;

  for (int ct = 0; ct < 32; ++ct) {
    const int cbase = half * 4096 + ct * 128;
    f32x4 acc[2][8];
#pragma unroll
    for (int m = 0; m < 2; ++m)
#pragma unroll
      for (int n = 0; n < 8; ++n) acc[m][n] = (f32x4){0.f, 0.f, 0.f, 0.f};

#pragma unroll
    for (int ch = 0; ch < 8; ++ch) {
      __syncthreads();
      {  // stage 128 codes x 32 dims, fp32 -> f16
        const float* s = cb + (cbase + stg_code) * DIMS + ch * 32 + stg_seg * 8;
        const float4 v0 = *(const float4*)s;
        const float4 v1 = *(const float4*)(s + 4);
        half8 h;
        h[0] = (_Float16)v0.x; h[1] = (_Float16)v0.y;
        h[2] = (_Float16)v0.z; h[3] = (_Float16)v0.w;
        h[4] = (_Float16)v1.x; h[5] = (_Float16)v1.y;
        h[6] = (_Float16)v1.z; h[7] = (_Float16)v1.w;
        *(half8*)&clds[stg_code][stg_seg * 8] = h;
      }
      __syncthreads();
      half8 b[8];
#pragma unroll
      for (int n = 0; n < 8; ++n)
        b[n] = *(const half8*)&clds[n * 16 + l15][lh * 8];
#pragma unroll
      for (int m = 0; m < 2; ++m)
#pragma unroll
        for (int n = 0; n < 8; ++n)
          acc[m][n] = __builtin_amdgcn_mfma_f32_16x16x32_f16(a[m][ch], b[n], acc[m][n], 0, 0, 0);
    }

    // Epilogue: per-row top-2 over this 128-code tile, merge into running.
    float cn[8];
#pragma unroll
    for (int n = 0; n < 8; ++n) cn[n] = cnorm[cbase + n * 16 + l15];

#pragma unroll
    for (int m = 0; m < 2; ++m) {
#pragma unroll
      for (int j = 0; j < 4; ++j) {
        float dv[8];
        float t1 = 3.0e38f, t2 = 3.0e38f;
#pragma unroll
        for (int n = 0; n < 8; ++n) {
          const float d = fmaf(-2.0f, acc[m][n][j], cn[n]);
          dv[n] = d;
          const float mx = fmaxf(t1, d);
          t1 = fminf(t1, d);
          t2 = fminf(t2, mx);
        }
        // top-2 merge across the 16 code-lanes
#pragma unroll
        for (int mk = 1; mk < 16; mk <<= 1) {
          const float o1 = __shfl_xor(t1, mk);
          const float o2 = __shfl_xor(t2, mk);
          const float hi = fmaxf(t1, o1);
          t1 = fminf(t1, o1);
          t2 = fminf(hi, fminf(t2, o2));
        }
        // index of tile min (lowest code on ties -> np.argmin semantics)
        int nidx = 0x7fffffff;
#pragma unroll
        for (int n = 0; n < 8; ++n)
          nidx = min(nidx, (dv[n] == t1) ? (cbase + n * 16 + l15) : 0x7fffffff);
#pragma unroll
        for (int mk = 1; mk < 16; mk <<= 1)
          nidx = min(nidx, __shfl_xor(nidx, mk));
        // merge (t1,t2,nidx) into running top-2; strict < keeps earlier (lower) idx
        const float hi2 = fmaxf(rd1[m][j], t1);
        const float lo = fminf(rd1[m][j], t1);
        rd2[m][j] = fminf(hi2, fminf(rd2[m][j], t2));
        ridx[m][j] = (t1 < rd1[m][j]) ? nidx : ridx[m][j];
        rd1[m][j] = lo;
      }
    }
  }

  if (l15 == 0) {
#pragma unroll
    for (int m = 0; m < 2; ++m) {
#pragma unroll
      for (int j = 0; j < 4; ++j) {
        const int rg = row0 + m * 16 + lh * 4 + j;
        d1h[half * NROWS + rg] = rd1[m][j];
        d2h[half * NROWS + rg] = rd2[m][j];
        idxh[half * NROWS + rg] = ridx[m][j];
      }
    }
  }
}

// ---------------------------------------------------------------------------
// K3: merge the two K-halves per row; flag near-ties for exact refinement.
// ---------------------------------------------------------------------------
__global__ void k_merge(const float* __restrict__ d1h, const float* __restrict__ d2h,
                        const int* __restrict__ idxh, unsigned* __restrict__ bestidx,
                        unsigned long long* __restrict__ bestkey,
                        int* __restrict__ wlist, int* __restrict__ wcount) {
  const int r = blockIdx.x * 256 + threadIdx.x;
  const float a1 = d1h[r], b1 = d1h[NROWS + r];
  const float a2 = d2h[r], b2 = d2h[NROWS + r];
  const int ia = idxh[r], ib = idxh[NROWS + r];
  const float lo = fminf(a1, b1);
  const float hi = fmaxf(a1, b1);
  const float d2 = fminf(hi, fminf(a2, b2));
  const int idx = (b1 < a1) ? ib : ia;  // tie -> half0 (lower codes)
  const bool flag = (d2 - lo) < MARGIN;
  bestidx[r] = (unsigned)idx | (flag ? 0x80000000u : 0u);
  if (flag) {
    bestkey[r] = ~0ull;
    const int wi = atomicAdd(wcount, 1);
    wlist[wi] = r;
  }
}

// ---------------------------------------------------------------------------
// K4: exact fp64 refinement. Code-sliced: block b owns codes [b*32, b*32+32),
// staged once to LDS; loops over flagged rows, atomicMin packed (dist,idx).
// ---------------------------------------------------------------------------
__launch_bounds__(256, 1)
__global__ void k_refine(const float* __restrict__ x, const float* __restrict__ cb,
                         const int* __restrict__ wlist, const int* __restrict__ wcount,
                         unsigned long long* __restrict__ bestkey) {
  __shared__ float cl[32][DIMS + 1];  // +1 pad
  const int tid = threadIdx.x;
  {
    const float* src = cb + blockIdx.x * 32 * DIMS;
#pragma unroll
    for (int i = 0; i < 32; ++i) {
      const int e = i * 256 + tid;
      cl[e >> 8][e & 255] = src[e];
    }
  }
  __syncthreads();
  const int nf = *wcount;
  const int ci = tid >> 3, piece = tid & 7;
  const int codeg = blockIdx.x * 32 + ci;
  for (int wi = 0; wi < nf; ++wi) {
    const int r = wlist[wi];
    const float* xr = x + r * DIMS;
    double s = 0.0;
#pragma unroll
    for (int i = 0; i < 32; ++i) {
      const int d = piece + i * 8;  // strided dims: avoids LDS bank pile-up
      const float diff = xr[d] - cl[ci][d];
      s = fma((double)diff, (double)diff, s);
    }
    s += __shfl_xor(s, 1);
    s += __shfl_xor(s, 2);
    s += __shfl_xor(s, 4);
    if (piece == 0) {
      const unsigned ub = __float_as_uint((float)s);  // dist >= 0: bits monotone
      atomicMin(bestkey + r, ((unsigned long long)ub << 32) | (unsigned long long)codeg);
    }
  }
}

// ---------------------------------------------------------------------------
// K5: gather quantized output + fused loss (1.25 * MSE).
// ---------------------------------------------------------------------------
__global__ void k_out(const float* __restrict__ x, const float* __restrict__ cb,
                      const unsigned* __restrict__ bestidx,
                      const unsigned long long* __restrict__ bestkey,
                      float* __restrict__ out, float* __restrict__ loss_cell) {
  const int gid = blockIdx.x * 256 + threadIdx.x;
  const int row = gid >> 6, d4 = gid & 63;
  const unsigned bi = bestidx[row];
  unsigned idx = bi & 0x7fffffffu;
  if (bi >> 31) idx = (unsigned)(bestkey[row] & 0xffffffffull);
  const float4 q = *(const float4*)(cb + idx * DIMS + d4 * 4);
  const float4 xv = *(const float4*)(x + gid * 4);
  *(float4*)(out + gid * 4) = q;
  const float dx = q.x - xv.x, dy = q.y - xv.y, dz = q.z - xv.z, dw = q.w - xv.w;
  float s = dx * dx + dy * dy + dz * dz + dw * dw;
#pragma unroll
  for (int m = 1; m < 64; m <<= 1) s += __shfl_xor(s, m);
  if ((threadIdx.x & 63) == 0)
    atomicAdd(loss_cell, s * (1.25f / (float)(NROWS * DIMS)));
}

// ---------------------------------------------------------------------------
extern "C" void kernel_launch(void* const* d_in, const int* in_sizes, int n_in,
                              void* d_out, int out_size, void* d_ws, size_t ws_size,
                              hipStream_t stream) {
  const float* x = (const float*)d_in[0];
  const float* cb = (const float*)d_in[1];
  float* out = (float*)d_out;
  char* ws = (char*)d_ws;

  float* cnorm = (float*)(ws + 0);                          //  32 KB
  float* d1h = (float*)(ws + 32768);                        // 256 KB
  float* d2h = (float*)(ws + 294912);                       // 256 KB
  int* idxh = (int*)(ws + 557056);                          // 256 KB
  unsigned* bestidx = (unsigned*)(ws + 819200);             // 128 KB
  unsigned long long* bestkey = (unsigned long long*)(ws + 950272);  // 256 KB
  int* wlist = (int*)(ws + 1212416);                        // 128 KB
  int* wcount = (int*)(ws + 1343488);                       //   4 B
  float* loss_cell = out + (NROWS * DIMS);

  k_cnorm<<<KCODES / 4, 256, 0, stream>>>(cb, cnorm, wcount, loss_cell);
  k_gemm<<<256, 512, 0, stream>>>(x, cb, cnorm, d1h, d2h, idxh);
  k_merge<<<NROWS / 256, 256, 0, stream>>>(d1h, d2h, idxh, bestidx, bestkey, wlist, wcount);
  k_refine<<<KCODES / 32, 256, 0, stream>>>(x, cb, wlist, wcount, bestkey);
  k_out<<<(NROWS * DIMS / 4) / 256, 256, 0, stream>>>(x, cb, bestidx, bestkey, out, loss_cell);
}

// Round 2
// 822.788 us; speedup vs baseline: 1.6500x; 1.6500x over previous
//
#include <hip/hip_runtime.h>
#include <hip/hip_fp16.h>

#define NROWS 32768
#define DIMS 256
#define KCODES 8192
#define MARGIN 0.10f

typedef _Float16 half8 __attribute__((ext_vector_type(8)));
typedef float f32x4 __attribute__((ext_vector_type(4)));

__device__ __forceinline__ void gload_lds16(const void* g, void* l) {
  __builtin_amdgcn_global_load_lds((const __attribute__((address_space(1))) unsigned int*)g,
                                   (__attribute__((address_space(3))) unsigned int*)l, 16, 0, 0);
}

__device__ __forceinline__ unsigned sortable_f32(float f) {
  unsigned u = __float_as_uint(f);
  return u ^ (unsigned)(((int)u >> 31) | 0x80000000);
}

// ---------------------------------------------------------------------------
// K0: fp32 codebook -> f16 codebook (RTN, same numerics as in-register cast).
// ---------------------------------------------------------------------------
__global__ void k_prep(const float* __restrict__ cb, _Float16* __restrict__ cbh) {
  const int g = blockIdx.x * 256 + threadIdx.x;  // 8 floats per thread
  const float4 v0 = *((const float4*)cb + g * 2);
  const float4 v1 = *((const float4*)cb + g * 2 + 1);
  half8 h;
  h[0] = (_Float16)v0.x; h[1] = (_Float16)v0.y;
  h[2] = (_Float16)v0.z; h[3] = (_Float16)v0.w;
  h[4] = (_Float16)v1.x; h[5] = (_Float16)v1.y;
  h[6] = (_Float16)v1.z; h[7] = (_Float16)v1.w;
  *((half8*)cbh + g) = h;
}

// ---------------------------------------------------------------------------
// K1: codebook squared norms; zero worklist counter and loss cell.
// ---------------------------------------------------------------------------
__global__ void k_cnorm(const float* __restrict__ cb, float* __restrict__ cnorm,
                        int* __restrict__ wcount, float* __restrict__ loss_cell) {
  const int lane = threadIdx.x & 63;
  const int code = blockIdx.x * 4 + (threadIdx.x >> 6);
  const float4 v = *((const float4*)(cb + code * DIMS) + lane);
  float s = v.x * v.x + v.y * v.y + v.z * v.z + v.w * v.w;
#pragma unroll
  for (int m = 1; m < 64; m <<= 1) s += __shfl_xor(s, m);
  if (lane == 0) cnorm[code] = s;
  if (blockIdx.x == 0 && threadIdx.x == 0) { *wcount = 0; *loss_cell = 0.0f; }
}

// ---------------------------------------------------------------------------
// K2 (fast): f16 MFMA distance GEMM, f16 codebook staged via global_load_lds
// into double-buffered swizzled LDS (2-way banks = free). One barrier/tile.
// Per-lane running top-2 + argmin (5 VALU/value); one cross-lane reduce at end.
// LDS granule map: G(code,ch,lh) = (ch*4+lh)*64 + (code ^ ((lh&1)<<4)).
// Read addr = lanebase +/- 256*(lh&1) + ch*4096 + n*256  (XOR folded into base).
// ---------------------------------------------------------------------------
__launch_bounds__(512, 2)
__global__ void k_gemm2(const float* __restrict__ x, const _Float16* __restrict__ cbh,
                        const float* __restrict__ cnorm,
                        float* __restrict__ d1h, float* __restrict__ d2h,
                        int* __restrict__ idxh) {
  __shared__ char B[2][32768];
  const int tid = threadIdx.x;
  const int lane = tid & 63;
  const int w = tid >> 6;
  const int l15 = lane & 15;
  const int lh = lane >> 4;
  const int rowblk = (int)blockIdx.x >> 1;
  const int half = (int)blockIdx.x & 1;
  const int row0 = rowblk * 256 + w * 32;
  const char* cbh_half = (const char*)(cbh + (size_t)half * 4096 * DIMS);

  // A fragments: x rows, fp32 -> f16 RTN, resident in VGPRs.
  half8 a[2][8];
#pragma unroll
  for (int m = 0; m < 2; ++m) {
#pragma unroll
    for (int kf = 0; kf < 8; ++kf) {
      const float* s = x + (size_t)(row0 + m * 16 + l15) * DIMS + kf * 32 + lh * 8;
      const float4 v0 = *(const float4*)s;
      const float4 v1 = *(const float4*)(s + 4);
      half8 h;
      h[0] = (_Float16)v0.x; h[1] = (_Float16)v0.y;
      h[2] = (_Float16)v0.z; h[3] = (_Float16)v0.w;
      h[4] = (_Float16)v1.x; h[5] = (_Float16)v1.y;
      h[6] = (_Float16)v1.z; h[7] = (_Float16)v1.w;
      a[m][kf] = h;
    }
  }

  // Staging source offsets (loop-invariant per thread): inverse of granule map.
  int srcoff[4];
#pragma unroll
  for (int i = 0; i < 4; ++i) {
    const int L = i * 512 + tid;  // granule index in 32KB tile
    const int hi = L >> 6;
    const int lhL = hi & 3, chL = hi >> 2;
    const int code = (L & 63) ^ ((lhL & 1) << 4);
    srcoff[i] = code * 512 + chL * 64 + lhL * 16;
  }

  const int lanebase = l15 * 16 + lh * 1024;
  const int bs = (lh & 1) << 8;
  const int lbp = lanebase + bs;  // for even n
  const int lbm = lanebase - bs;  // for odd n

  float r1[2][4], r2[2][4];
  int i1[2][4];
#pragma unroll
  for (int m = 0; m < 2; ++m)
#pragma unroll
    for (int j = 0; j < 4; ++j) { r1[m][j] = 3.0e38f; r2[m][j] = 3.0e38f; i1[m][j] = 0; }

  char* lds = &B[0][0];

  auto stage = [&](int t, int bufoff) {
#pragma unroll
    for (int i = 0; i < 4; ++i)
      gload_lds16(cbh_half + t * 32768 + srcoff[i],
                  lds + bufoff + (i * 512 + w * 64) * 16);
  };

  auto compute_tile = [&](int t, int bufoff) {
    const int cbase = half * 4096 + t * 64;
    float cn[4];
#pragma unroll
    for (int n = 0; n < 4; ++n) cn[n] = cnorm[cbase + n * 16 + l15];
    f32x4 acc[2][4];
#pragma unroll
    for (int m = 0; m < 2; ++m)
#pragma unroll
      for (int n = 0; n < 4; ++n) acc[m][n] = (f32x4){0.f, 0.f, 0.f, 0.f};
#pragma unroll
    for (int ch = 0; ch < 8; ++ch) {
      half8 b[4];
#pragma unroll
      for (int n = 0; n < 4; ++n) {
        const int ad = ((n & 1) ? lbm : lbp) + bufoff + ch * 4096 + n * 256;
        b[n] = *(const half8*)(lds + ad);
      }
#pragma unroll
      for (int m = 0; m < 2; ++m)
#pragma unroll
        for (int n = 0; n < 4; ++n)
          acc[m][n] = __builtin_amdgcn_mfma_f32_16x16x32_f16(a[m][ch], b[n], acc[m][n], 0, 0, 0);
    }
    // Epilogue: 5 ops/value, per-lane running top-2 + packed argmin (t*4+n).
#pragma unroll
    for (int m = 0; m < 2; ++m)
#pragma unroll
      for (int n = 0; n < 4; ++n) {
        const int ic = t * 4 + n;
#pragma unroll
        for (int j = 0; j < 4; ++j) {
          const float d = fmaf(-2.0f, acc[m][n][j], cn[n]);
          r2[m][j] = __builtin_amdgcn_fmed3f(d, r1[m][j], r2[m][j]);
          i1[m][j] = (d < r1[m][j]) ? ic : i1[m][j];
          r1[m][j] = fminf(r1[m][j], d);
        }
      }
  };

  stage(0, 0);
#pragma unroll 1
  for (int t = 0; t < 64; t += 2) {
    __syncthreads();
    if (t + 1 < 64) stage(t + 1, 32768);
    compute_tile(t, 0);
    __syncthreads();
    if (t + 2 < 64) stage(t + 2, 0);
    compute_tile(t + 1, 32768);
  }

  // Final cross-lane reduce (once): u64 (dist,code) min + top-2 floats.
#pragma unroll
  for (int m = 0; m < 2; ++m)
#pragma unroll
    for (int j = 0; j < 4; ++j) {
      const int code = half * 4096 + (i1[m][j] >> 2) * 64 + (i1[m][j] & 3) * 16 + l15;
      unsigned long long key =
          ((unsigned long long)sortable_f32(r1[m][j]) << 32) | (unsigned)code;
      float t1 = r1[m][j], t2 = r2[m][j];
#pragma unroll
      for (int mk = 1; mk < 16; mk <<= 1) {
        const unsigned long long ok = __shfl_xor(key, mk);
        const float o1 = __shfl_xor(t1, mk);
        const float o2 = __shfl_xor(t2, mk);
        t2 = fminf(fmaxf(t1, o1), fminf(t2, o2));
        t1 = fminf(t1, o1);
        key = (ok < key) ? ok : key;
      }
      if (l15 == 0) {
        const int rg = row0 + m * 16 + lh * 4 + j;
        d1h[half * NROWS + rg] = t1;
        d2h[half * NROWS + rg] = t2;
        idxh[half * NROWS + rg] = (int)(unsigned)(key & 0xffffffffull);
      }
    }
}

// ---------------------------------------------------------------------------
// K2 (fallback, ws too small): round-1 GEMM, converts in-kernel, padded LDS.
// ---------------------------------------------------------------------------
__launch_bounds__(512, 2)
__global__ void k_gemm(const float* __restrict__ x, const float* __restrict__ cb,
                       const float* __restrict__ cnorm,
                       float* __restrict__ d1h, float* __restrict__ d2h,
                       int* __restrict__ idxh) {
  __shared__ _Float16 clds[128][40];
  const int tid = threadIdx.x;
  const int lane = tid & 63;
  const int w = tid >> 6;
  const int l15 = lane & 15;
  const int lh = lane >> 4;
  const int rowblk = (int)blockIdx.x >> 1;
  const int half = (int)blockIdx.x & 1;
  const int row0 = rowblk * 256 + w * 32;

  half8 a[2][8];
#pragma unroll
  for (int m = 0; m < 2; ++m) {
#pragma unroll
    for (int kf = 0; kf < 8; ++kf) {
      const float* s = x + (row0 + m * 16 + l15) * DIMS + kf * 32 + lh * 8;
      const float4 v0 = *(const float4*)s;
      const float4 v1 = *(const float4*)(s + 4);
      half8 h;
      h[0] = (_Float16)v0.x; h[1] = (_Float16)v0.y;
      h[2] = (_Float16)v0.z; h[3] = (_Float16)v0.w;
      h[4] = (_Float16)v1.x; h[5] = (_Float16)v1.y;
      h[6] = (_Float16)v1.z; h[7] = (_Float16)v1.w;
      a[m][kf] = h;
    }
  }

  float r1[2][4], r2[2][4];
  int i1[2][4];
#pragma unroll
  for (int m = 0; m < 2; ++m)
#pragma unroll
    for (int j = 0; j < 4; ++j) { r1[m][j] = 3.0e38f; r2[m][j] = 3.0e38f; i1[m][j] = 0; }

  const int stg_code = tid >> 2;
  const int stg_seg = tid & 3;

  for (int ct = 0; ct < 32; ++ct) {
    const int cbase = half * 4096 + ct * 128;
    f32x4 acc[2][8];
#pragma unroll
    for (int m = 0; m < 2; ++m)
#pragma unroll
      for (int n = 0; n < 8; ++n) acc[m][n] = (f32x4){0.f, 0.f, 0.f, 0.f};

#pragma unroll
    for (int ch = 0; ch < 8; ++ch) {
      __syncthreads();
      {
        const float* s = cb + (cbase + stg_code) * DIMS + ch * 32 + stg_seg * 8;
        const float4 v0 = *(const float4*)s;
        const float4 v1 = *(const float4*)(s + 4);
        half8 h;
        h[0] = (_Float16)v0.x; h[1] = (_Float16)v0.y;
        h[2] = (_Float16)v0.z; h[3] = (_Float16)v0.w;
        h[4] = (_Float16)v1.x; h[5] = (_Float16)v1.y;
        h[6] = (_Float16)v1.z; h[7] = (_Float16)v1.w;
        *(half8*)&clds[stg_code][stg_seg * 8] = h;
      }
      __syncthreads();
      half8 b[8];
#pragma unroll
      for (int n = 0; n < 8; ++n)
        b[n] = *(const half8*)&clds[n * 16 + l15][lh * 8];
#pragma unroll
      for (int m = 0; m < 2; ++m)
#pragma unroll
        for (int n = 0; n < 8; ++n)
          acc[m][n] = __builtin_amdgcn_mfma_f32_16x16x32_f16(a[m][ch], b[n], acc[m][n], 0, 0, 0);
    }

    float cn[8];
#pragma unroll
    for (int n = 0; n < 8; ++n) cn[n] = cnorm[cbase + n * 16 + l15];
#pragma unroll
    for (int m = 0; m < 2; ++m)
#pragma unroll
      for (int n = 0; n < 8; ++n) {
        const int ic = ct * 8 + n;
#pragma unroll
        for (int j = 0; j < 4; ++j) {
          const float d = fmaf(-2.0f, acc[m][n][j], cn[n]);
          r2[m][j] = __builtin_amdgcn_fmed3f(d, r1[m][j], r2[m][j]);
          i1[m][j] = (d < r1[m][j]) ? ic : i1[m][j];
          r1[m][j] = fminf(r1[m][j], d);
        }
      }
  }

#pragma unroll
  for (int m = 0; m < 2; ++m)
#pragma unroll
    for (int j = 0; j < 4; ++j) {
      const int code = half * 4096 + (i1[m][j] >> 3) * 128 + (i1[m][j] & 7) * 16 + l15;
      unsigned long long key =
          ((unsigned long long)sortable_f32(r1[m][j]) << 32) | (unsigned)code;
      float t1 = r1[m][j], t2 = r2[m][j];
#pragma unroll
      for (int mk = 1; mk < 16; mk <<= 1) {
        const unsigned long long ok = __shfl_xor(key, mk);
        const float o1 = __shfl_xor(t1, mk);
        const float o2 = __shfl_xor(t2, mk);
        t2 = fminf(fmaxf(t1, o1), fminf(t2, o2));
        t1 = fminf(t1, o1);
        key = (ok < key) ? ok : key;
      }
      if (l15 == 0) {
        const int rg = row0 + m * 16 + lh * 4 + j;
        d1h[half * NROWS + rg] = t1;
        d2h[half * NROWS + rg] = t2;
        idxh[half * NROWS + rg] = (int)(unsigned)(key & 0xffffffffull);
      }
    }
}

// ---------------------------------------------------------------------------
// K3: merge the two K-halves per row; flag near-ties for exact refinement.
// ---------------------------------------------------------------------------
__global__ void k_merge(const float* __restrict__ d1h, const float* __restrict__ d2h,
                        const int* __restrict__ idxh, unsigned* __restrict__ bestidx,
                        unsigned long long* __restrict__ bestkey,
                        int* __restrict__ wlist, int* __restrict__ wcount) {
  const int r = blockIdx.x * 256 + threadIdx.x;
  const float a1 = d1h[r], b1 = d1h[NROWS + r];
  const float a2 = d2h[r], b2 = d2h[NROWS + r];
  const int ia = idxh[r], ib = idxh[NROWS + r];
  const float lo = fminf(a1, b1);
  const float hi = fmaxf(a1, b1);
  const float d2 = fminf(hi, fminf(a2, b2));
  const int idx = (b1 < a1) ? ib : ia;
  const bool flag = (d2 - lo) < MARGIN;
  bestidx[r] = (unsigned)idx | (flag ? 0x80000000u : 0u);
  if (flag) {
    bestkey[r] = ~0ull;
    const int wi = atomicAdd(wcount, 1);
    wlist[wi] = r;
  }
}

// ---------------------------------------------------------------------------
// K4: exact refinement v2. Block b owns codes [b*32,b*32+32) in LDS (fp32).
// Row-parallel: 512 thr = 32 codes x 16 pieces; fp32 16-term chains, fp64
// cross-piece reduce; staggered row start + read-gated atomicMin.
// ---------------------------------------------------------------------------
__launch_bounds__(512, 1)
__global__ void k_refine2(const float* __restrict__ x, const float* __restrict__ cb,
                          const int* __restrict__ wlist, const int* __restrict__ wcount,
                          unsigned long long* __restrict__ bestkey) {
  __shared__ float cl[32 * 260];
  __shared__ float xl[2][16][20];
  const int tid = threadIdx.x;
  const int ci = tid >> 4;
  const int piece = tid & 15;
#pragma unroll
  for (int i = 0; i < 16; ++i) {
    const int e = i * 512 + tid;
    cl[(e >> 8) * 260 + (e & 255)] = cb[(size_t)blockIdx.x * 32 * DIMS + e];
  }
  const int nf = *wcount;
  if (nf == 0) return;
  const int codeg = blockIdx.x * 32 + ci;
  const int start = (int)(((long long)blockIdx.x * nf) >> 8);

  {
    const int r0 = wlist[start];
    if (tid < 256) xl[0][tid >> 4][tid & 15] = x[(size_t)r0 * DIMS + tid];
  }
  __syncthreads();

  for (int k = 0; k < nf; ++k) {
    const int cur = k & 1;
    if (k + 1 < nf) {
      int nxt = start + k + 1;
      if (nxt >= nf) nxt -= nf;
      const int rn = wlist[nxt];
      if (tid < 256) xl[cur ^ 1][tid >> 4][tid & 15] = x[(size_t)rn * DIMS + tid];
    }
    int idx0 = start + k;
    if (idx0 >= nf) idx0 -= nf;
    const int row = wlist[idx0];

    const float* cp = &cl[ci * 260 + piece * 16];
    const float* xp = &xl[cur][piece][0];
    float s = 0.f;
#pragma unroll
    for (int q = 0; q < 16; ++q) {
      const float df = xp[q] - cp[q];
      s = fmaf(df, df, s);
    }
    double ds = (double)s;
    ds += __shfl_xor(ds, 1);
    ds += __shfl_xor(ds, 2);
    ds += __shfl_xor(ds, 4);
    ds += __shfl_xor(ds, 8);
    if (piece == 0) {
      const float dist = (float)ds;
      const unsigned long long key =
          ((unsigned long long)__float_as_uint(dist) << 32) | (unsigned)codeg;
      if (key < bestkey[row]) atomicMin(&bestkey[row], key);
    }
    __syncthreads();
  }
}

// ---------------------------------------------------------------------------
// K5: gather quantized output + fused loss (1.25 * MSE).
// ---------------------------------------------------------------------------
__global__ void k_out(const float* __restrict__ x, const float* __restrict__ cb,
                      const unsigned* __restrict__ bestidx,
                      const unsigned long long* __restrict__ bestkey,
                      float* __restrict__ out, float* __restrict__ loss_cell) {
  const int gid = blockIdx.x * 256 + threadIdx.x;
  const int row = gid >> 6, d4 = gid & 63;
  const unsigned bi = bestidx[row];
  unsigned idx = bi & 0x7fffffffu;
  if (bi >> 31) idx = (unsigned)(bestkey[row] & 0xffffffffull);
  const float4 q = *(const float4*)(cb + (size_t)idx * DIMS + d4 * 4);
  const float4 xv = *(const float4*)(x + (size_t)gid * 4);
  *(float4*)(out + (size_t)gid * 4) = q;
  const float dx = q.x - xv.x, dy = q.y - xv.y, dz = q.z - xv.z, dw = q.w - xv.w;
  float s = dx * dx + dy * dy + dz * dz + dw * dw;
#pragma unroll
  for (int m = 1; m < 64; m <<= 1) s += __shfl_xor(s, m);
  if ((threadIdx.x & 63) == 0)
    atomicAdd(loss_cell, s * (1.25f / (float)(NROWS * DIMS)));
}

// ---------------------------------------------------------------------------
extern "C" void kernel_launch(void* const* d_in, const int* in_sizes, int n_in,
                              void* d_out, int out_size, void* d_ws, size_t ws_size,
                              hipStream_t stream) {
  const float* x = (const float*)d_in[0];
  const float* cb = (const float*)d_in[1];
  float* out = (float*)d_out;
  char* ws = (char*)d_ws;

  float* cnorm = (float*)(ws + 0);
  float* d1h = (float*)(ws + 32768);
  float* d2h = (float*)(ws + 294912);
  int* idxh = (int*)(ws + 557056);
  unsigned* bestidx = (unsigned*)(ws + 819200);
  unsigned long long* bestkey = (unsigned long long*)(ws + 950272);
  int* wlist = (int*)(ws + 1212416);
  int* wcount = (int*)(ws + 1343488);
  _Float16* cbh = (_Float16*)(ws + 1376256);  // 4 MB, fast path only
  float* loss_cell = out + (NROWS * DIMS);

  const bool fast = ws_size >= (size_t)(1376256 + KCODES * DIMS * 2);

  k_cnorm<<<KCODES / 4, 256, 0, stream>>>(cb, cnorm, wcount, loss_cell);
  if (fast) {
    k_prep<<<KCODES * DIMS / 8 / 256, 256, 0, stream>>>(cb, cbh);
    k_gemm2<<<256, 512, 0, stream>>>(x, cbh, cnorm, d1h, d2h, idxh);
  } else {
    k_gemm<<<256, 512, 0, stream>>>(x, cb, cnorm, d1h, d2h, idxh);
  }
  k_merge<<<NROWS / 256, 256, 0, stream>>>(d1h, d2h, idxh, bestidx, bestkey, wlist, wcount);
  k_refine2<<<KCODES / 32, 512, 0, stream>>>(x, cb, wlist, wcount, bestkey);
  k_out<<<(NROWS * DIMS / 4) / 256, 256, 0, stream>>>(x, cb, bestidx, bestkey, out, loss_cell);
}

// Round 3
// 419.274 us; speedup vs baseline: 3.2381x; 1.9624x over previous
//
#include <hip/hip_runtime.h>
#include <hip/hip_fp16.h>

#define NROWS 32768
#define DIMS 256
#define KCODES 8192
#define MARGIN 0.10f

typedef _Float16 half8 __attribute__((ext_vector_type(8)));
typedef float f32x4 __attribute__((ext_vector_type(4)));

__device__ __forceinline__ void gload_lds16(const void* g, void* l) {
  __builtin_amdgcn_global_load_lds((const __attribute__((address_space(1))) unsigned int*)g,
                                   (__attribute__((address_space(3))) unsigned int*)l, 16, 0, 0);
}

__device__ __forceinline__ unsigned sortable_f32(float f) {
  unsigned u = __float_as_uint(f);
  return u ^ (unsigned)(((int)u >> 31) | 0x80000000);
}

// ---------------------------------------------------------------------------
// K0: fp32 codebook -> f16 codebook (RTN, same numerics as in-register cast).
// ---------------------------------------------------------------------------
__global__ void k_prep(const float* __restrict__ cb, _Float16* __restrict__ cbh) {
  const int g = blockIdx.x * 256 + threadIdx.x;  // 8 floats per thread
  const float4 v0 = *((const float4*)cb + g * 2);
  const float4 v1 = *((const float4*)cb + g * 2 + 1);
  half8 h;
  h[0] = (_Float16)v0.x; h[1] = (_Float16)v0.y;
  h[2] = (_Float16)v0.z; h[3] = (_Float16)v0.w;
  h[4] = (_Float16)v1.x; h[5] = (_Float16)v1.y;
  h[6] = (_Float16)v1.z; h[7] = (_Float16)v1.w;
  *((half8*)cbh + g) = h;
}

// ---------------------------------------------------------------------------
// K1: codebook squared norms; zero worklist counter and loss cell.
// ---------------------------------------------------------------------------
__global__ void k_cnorm(const float* __restrict__ cb, float* __restrict__ cnorm,
                        int* __restrict__ wcount, float* __restrict__ loss_cell) {
  const int lane = threadIdx.x & 63;
  const int code = blockIdx.x * 4 + (threadIdx.x >> 6);
  const float4 v = *((const float4*)(cb + code * DIMS) + lane);
  float s = v.x * v.x + v.y * v.y + v.z * v.z + v.w * v.w;
#pragma unroll
  for (int m = 1; m < 64; m <<= 1) s += __shfl_xor(s, m);
  if (lane == 0) cnorm[code] = s;
  if (blockIdx.x == 0 && threadIdx.x == 0) { *wcount = 0; *loss_cell = 0.0f; }
}

// ---------------------------------------------------------------------------
// K2 (fast): f16 MFMA distance GEMM, f16 codebook staged via global_load_lds
// into double-buffered swizzled LDS (2-way banks = free). One barrier/tile.
// Per-lane running top-2 + argmin (5 VALU/value); one cross-lane reduce at end.
// ---------------------------------------------------------------------------
__launch_bounds__(512, 2)
__global__ void k_gemm2(const float* __restrict__ x, const _Float16* __restrict__ cbh,
                        const float* __restrict__ cnorm,
                        float* __restrict__ d1h, float* __restrict__ d2h,
                        int* __restrict__ idxh) {
  __shared__ char B[2][32768];
  const int tid = threadIdx.x;
  const int lane = tid & 63;
  const int w = tid >> 6;
  const int l15 = lane & 15;
  const int lh = lane >> 4;
  const int rowblk = (int)blockIdx.x >> 1;
  const int half = (int)blockIdx.x & 1;
  const int row0 = rowblk * 256 + w * 32;
  const char* cbh_half = (const char*)(cbh + (size_t)half * 4096 * DIMS);

  // A fragments: x rows, fp32 -> f16 RTN, resident in VGPRs.
  half8 a[2][8];
#pragma unroll
  for (int m = 0; m < 2; ++m) {
#pragma unroll
    for (int kf = 0; kf < 8; ++kf) {
      const float* s = x + (size_t)(row0 + m * 16 + l15) * DIMS + kf * 32 + lh * 8;
      const float4 v0 = *(const float4*)s;
      const float4 v1 = *(const float4*)(s + 4);
      half8 h;
      h[0] = (_Float16)v0.x; h[1] = (_Float16)v0.y;
      h[2] = (_Float16)v0.z; h[3] = (_Float16)v0.w;
      h[4] = (_Float16)v1.x; h[5] = (_Float16)v1.y;
      h[6] = (_Float16)v1.z; h[7] = (_Float16)v1.w;
      a[m][kf] = h;
    }
  }

  // Staging source offsets (loop-invariant per thread): inverse of granule map.
  int srcoff[4];
#pragma unroll
  for (int i = 0; i < 4; ++i) {
    const int L = i * 512 + tid;  // granule index in 32KB tile
    const int hi = L >> 6;
    const int lhL = hi & 3, chL = hi >> 2;
    const int code = (L & 63) ^ ((lhL & 1) << 4);
    srcoff[i] = code * 512 + chL * 64 + lhL * 16;
  }

  const int lanebase = l15 * 16 + lh * 1024;
  const int bs = (lh & 1) << 8;
  const int lbp = lanebase + bs;  // for even n
  const int lbm = lanebase - bs;  // for odd n

  float r1[2][4], r2[2][4];
  int i1[2][4];
#pragma unroll
  for (int m = 0; m < 2; ++m)
#pragma unroll
    for (int j = 0; j < 4; ++j) { r1[m][j] = 3.0e38f; r2[m][j] = 3.0e38f; i1[m][j] = 0; }

  char* lds = &B[0][0];

  auto stage = [&](int t, int bufoff) {
#pragma unroll
    for (int i = 0; i < 4; ++i)
      gload_lds16(cbh_half + t * 32768 + srcoff[i],
                  lds + bufoff + (i * 512 + w * 64) * 16);
  };

  auto compute_tile = [&](int t, int bufoff) {
    const int cbase = half * 4096 + t * 64;
    float cn[4];
#pragma unroll
    for (int n = 0; n < 4; ++n) cn[n] = cnorm[cbase + n * 16 + l15];
    f32x4 acc[2][4];
#pragma unroll
    for (int m = 0; m < 2; ++m)
#pragma unroll
      for (int n = 0; n < 4; ++n) acc[m][n] = (f32x4){0.f, 0.f, 0.f, 0.f};
#pragma unroll
    for (int ch = 0; ch < 8; ++ch) {
      half8 b[4];
#pragma unroll
      for (int n = 0; n < 4; ++n) {
        const int ad = ((n & 1) ? lbm : lbp) + bufoff + ch * 4096 + n * 256;
        b[n] = *(const half8*)(lds + ad);
      }
#pragma unroll
      for (int m = 0; m < 2; ++m)
#pragma unroll
        for (int n = 0; n < 4; ++n)
          acc[m][n] = __builtin_amdgcn_mfma_f32_16x16x32_f16(a[m][ch], b[n], acc[m][n], 0, 0, 0);
    }
#pragma unroll
    for (int m = 0; m < 2; ++m)
#pragma unroll
      for (int n = 0; n < 4; ++n) {
        const int ic = t * 4 + n;
#pragma unroll
        for (int j = 0; j < 4; ++j) {
          const float d = fmaf(-2.0f, acc[m][n][j], cn[n]);
          r2[m][j] = __builtin_amdgcn_fmed3f(d, r1[m][j], r2[m][j]);
          i1[m][j] = (d < r1[m][j]) ? ic : i1[m][j];
          r1[m][j] = fminf(r1[m][j], d);
        }
      }
  };

  stage(0, 0);
#pragma unroll 1
  for (int t = 0; t < 64; t += 2) {
    __syncthreads();
    if (t + 1 < 64) stage(t + 1, 32768);
    compute_tile(t, 0);
    __syncthreads();
    if (t + 2 < 64) stage(t + 2, 0);
    compute_tile(t + 1, 32768);
  }

  // Final cross-lane reduce (once): u64 (dist,code) min + top-2 floats.
#pragma unroll
  for (int m = 0; m < 2; ++m)
#pragma unroll
    for (int j = 0; j < 4; ++j) {
      const int code = half * 4096 + (i1[m][j] >> 2) * 64 + (i1[m][j] & 3) * 16 + l15;
      unsigned long long key =
          ((unsigned long long)sortable_f32(r1[m][j]) << 32) | (unsigned)code;
      float t1 = r1[m][j], t2 = r2[m][j];
#pragma unroll
      for (int mk = 1; mk < 16; mk <<= 1) {
        const unsigned long long ok = __shfl_xor(key, mk);
        const float o1 = __shfl_xor(t1, mk);
        const float o2 = __shfl_xor(t2, mk);
        t2 = fminf(fmaxf(t1, o1), fminf(t2, o2));
        t1 = fminf(t1, o1);
        key = (ok < key) ? ok : key;
      }
      if (l15 == 0) {
        const int rg = row0 + m * 16 + lh * 4 + j;
        d1h[half * NROWS + rg] = t1;
        d2h[half * NROWS + rg] = t2;
        idxh[half * NROWS + rg] = (int)(unsigned)(key & 0xffffffffull);
      }
    }
}

// ---------------------------------------------------------------------------
// K2 (fallback, ws too small): converts in-kernel, padded LDS.
// ---------------------------------------------------------------------------
__launch_bounds__(512, 2)
__global__ void k_gemm(const float* __restrict__ x, const float* __restrict__ cb,
                       const float* __restrict__ cnorm,
                       float* __restrict__ d1h, float* __restrict__ d2h,
                       int* __restrict__ idxh) {
  __shared__ _Float16 clds[128][40];
  const int tid = threadIdx.x;
  const int lane = tid & 63;
  const int w = tid >> 6;
  const int l15 = lane & 15;
  const int lh = lane >> 4;
  const int rowblk = (int)blockIdx.x >> 1;
  const int half = (int)blockIdx.x & 1;
  const int row0 = rowblk * 256 + w * 32;

  half8 a[2][8];
#pragma unroll
  for (int m = 0; m < 2; ++m) {
#pragma unroll
    for (int kf = 0; kf < 8; ++kf) {
      const float* s = x + (row0 + m * 16 + l15) * DIMS + kf * 32 + lh * 8;
      const float4 v0 = *(const float4*)s;
      const float4 v1 = *(const float4*)(s + 4);
      half8 h;
      h[0] = (_Float16)v0.x; h[1] = (_Float16)v0.y;
      h[2] = (_Float16)v0.z; h[3] = (_Float16)v0.w;
      h[4] = (_Float16)v1.x; h[5] = (_Float16)v1.y;
      h[6] = (_Float16)v1.z; h[7] = (_Float16)v1.w;
      a[m][kf] = h;
    }
  }

  float r1[2][4], r2[2][4];
  int i1[2][4];
#pragma unroll
  for (int m = 0; m < 2; ++m)
#pragma unroll
    for (int j = 0; j < 4; ++j) { r1[m][j] = 3.0e38f; r2[m][j] = 3.0e38f; i1[m][j] = 0; }

  const int stg_code = tid >> 2;
  const int stg_seg = tid & 3;

  for (int ct = 0; ct < 32; ++ct) {
    const int cbase = half * 4096 + ct * 128;
    f32x4 acc[2][8];
#pragma unroll
    for (int m = 0; m < 2; ++m)
#pragma unroll
      for (int n = 0; n < 8; ++n) acc[m][n] = (f32x4){0.f, 0.f, 0.f, 0.f};

#pragma unroll
    for (int ch = 0; ch < 8; ++ch) {
      __syncthreads();
      {
        const float* s = cb + (cbase + stg_code) * DIMS + ch * 32 + stg_seg * 8;
        const float4 v0 = *(const float4*)s;
        const float4 v1 = *(const float4*)(s + 4);
        half8 h;
        h[0] = (_Float16)v0.x; h[1] = (_Float16)v0.y;
        h[2] = (_Float16)v0.z; h[3] = (_Float16)v0.w;
        h[4] = (_Float16)v1.x; h[5] = (_Float16)v1.y;
        h[6] = (_Float16)v1.z; h[7] = (_Float16)v1.w;
        *(half8*)&clds[stg_code][stg_seg * 8] = h;
      }
      __syncthreads();
      half8 b[8];
#pragma unroll
      for (int n = 0; n < 8; ++n)
        b[n] = *(const half8*)&clds[n * 16 + l15][lh * 8];
#pragma unroll
      for (int m = 0; m < 2; ++m)
#pragma unroll
        for (int n = 0; n < 8; ++n)
          acc[m][n] = __builtin_amdgcn_mfma_f32_16x16x32_f16(a[m][ch], b[n], acc[m][n], 0, 0, 0);
    }

    float cn[8];
#pragma unroll
    for (int n = 0; n < 8; ++n) cn[n] = cnorm[cbase + n * 16 + l15];
#pragma unroll
    for (int m = 0; m < 2; ++m)
#pragma unroll
      for (int n = 0; n < 8; ++n) {
        const int ic = ct * 8 + n;
#pragma unroll
        for (int j = 0; j < 4; ++j) {
          const float d = fmaf(-2.0f, acc[m][n][j], cn[n]);
          r2[m][j] = __builtin_amdgcn_fmed3f(d, r1[m][j], r2[m][j]);
          i1[m][j] = (d < r1[m][j]) ? ic : i1[m][j];
          r1[m][j] = fminf(r1[m][j], d);
        }
      }
  }

#pragma unroll
  for (int m = 0; m < 2; ++m)
#pragma unroll
    for (int j = 0; j < 4; ++j) {
      const int code = half * 4096 + (i1[m][j] >> 3) * 128 + (i1[m][j] & 7) * 16 + l15;
      unsigned long long key =
          ((unsigned long long)sortable_f32(r1[m][j]) << 32) | (unsigned)code;
      float t1 = r1[m][j], t2 = r2[m][j];
#pragma unroll
      for (int mk = 1; mk < 16; mk <<= 1) {
        const unsigned long long ok = __shfl_xor(key, mk);
        const float o1 = __shfl_xor(t1, mk);
        const float o2 = __shfl_xor(t2, mk);
        t2 = fminf(fmaxf(t1, o1), fminf(t2, o2));
        t1 = fminf(t1, o1);
        key = (ok < key) ? ok : key;
      }
      if (l15 == 0) {
        const int rg = row0 + m * 16 + lh * 4 + j;
        d1h[half * NROWS + rg] = t1;
        d2h[half * NROWS + rg] = t2;
        idxh[half * NROWS + rg] = (int)(unsigned)(key & 0xffffffffull);
      }
    }
}

// ---------------------------------------------------------------------------
// K3: merge the two K-halves per row; flag near-ties for exact refinement.
// ---------------------------------------------------------------------------
__global__ void k_merge(const float* __restrict__ d1h, const float* __restrict__ d2h,
                        const int* __restrict__ idxh, unsigned* __restrict__ bestidx,
                        unsigned long long* __restrict__ bestkey,
                        int* __restrict__ wlist, int* __restrict__ wcount) {
  const int r = blockIdx.x * 256 + threadIdx.x;
  const float a1 = d1h[r], b1 = d1h[NROWS + r];
  const float a2 = d2h[r], b2 = d2h[NROWS + r];
  const int ia = idxh[r], ib = idxh[NROWS + r];
  const float lo = fminf(a1, b1);
  const float hi = fmaxf(a1, b1);
  const float d2 = fminf(hi, fminf(a2, b2));
  const int idx = (b1 < a1) ? ib : ia;
  const bool flag = (d2 - lo) < MARGIN;
  bestidx[r] = (unsigned)idx | (flag ? 0x80000000u : 0u);
  if (flag) {
    bestkey[r] = ~0ull;
    const int wi = atomicAdd(wcount, 1);
    wlist[wi] = r;
  }
}

// ---------------------------------------------------------------------------
// K4: exact refinement v2. Block b owns codes [b*32,b*32+32) in LDS (fp32).
// Row-parallel: 512 thr = 32 codes x 16 pieces; staggered row start +
// read-gated atomicMin.
// ---------------------------------------------------------------------------
__launch_bounds__(512, 1)
__global__ void k_refine2(const float* __restrict__ x, const float* __restrict__ cb,
                          const int* __restrict__ wlist, const int* __restrict__ wcount,
                          unsigned long long* __restrict__ bestkey) {
  __shared__ float cl[32 * 260];
  __shared__ float xl[2][16][20];
  const int tid = threadIdx.x;
  const int ci = tid >> 4;
  const int piece = tid & 15;
#pragma unroll
  for (int i = 0; i < 16; ++i) {
    const int e = i * 512 + tid;
    cl[(e >> 8) * 260 + (e & 255)] = cb[(size_t)blockIdx.x * 32 * DIMS + e];
  }
  const int nf = *wcount;
  if (nf == 0) return;
  const int codeg = blockIdx.x * 32 + ci;
  const int start = (int)(((long long)blockIdx.x * nf) >> 8);

  {
    const int r0 = wlist[start];
    if (tid < 256) xl[0][tid >> 4][tid & 15] = x[(size_t)r0 * DIMS + tid];
  }
  __syncthreads();

  for (int k = 0; k < nf; ++k) {
    const int cur = k & 1;
    if (k + 1 < nf) {
      int nxt = start + k + 1;
      if (nxt >= nf) nxt -= nf;
      const int rn = wlist[nxt];
      if (tid < 256) xl[cur ^ 1][tid >> 4][tid & 15] = x[(size_t)rn * DIMS + tid];
    }
    int idx0 = start + k;
    if (idx0 >= nf) idx0 -= nf;
    const int row = wlist[idx0];

    const float* cp = &cl[ci * 260 + piece * 16];
    const float* xp = &xl[cur][piece][0];
    float s = 0.f;
#pragma unroll
    for (int q = 0; q < 16; ++q) {
      const float df = xp[q] - cp[q];
      s = fmaf(df, df, s);
    }
    double ds = (double)s;
    ds += __shfl_xor(ds, 1);
    ds += __shfl_xor(ds, 2);
    ds += __shfl_xor(ds, 4);
    ds += __shfl_xor(ds, 8);
    if (piece == 0) {
      const float dist = (float)ds;
      const unsigned long long key =
          ((unsigned long long)__float_as_uint(dist) << 32) | (unsigned)codeg;
      if (key < bestkey[row]) atomicMin(&bestkey[row], key);
    }
    __syncthreads();
  }
}

// ---------------------------------------------------------------------------
// K5: gather quantized output + per-block loss partials (NO global atomics).
// 2048 blocks x 256 thr, grid-stride 4 float4/thread.
// ---------------------------------------------------------------------------
__launch_bounds__(256)
__global__ void k_out2(const float* __restrict__ x, const float* __restrict__ cb,
                       const unsigned* __restrict__ bestidx,
                       const unsigned long long* __restrict__ bestkey,
                       float* __restrict__ out, float* __restrict__ partials) {
  __shared__ float wsum[4];
  float s = 0.f;
#pragma unroll
  for (int it = 0; it < 4; ++it) {
    const int gid = (it * 2048 + blockIdx.x) * 256 + threadIdx.x;
    const int row = gid >> 6, d4 = gid & 63;
    const unsigned bi = bestidx[row];
    unsigned idx = bi & 0x7fffffffu;
    if (bi >> 31) idx = (unsigned)(bestkey[row] & 0xffffffffull);
    const float4 q = *(const float4*)(cb + (size_t)idx * DIMS + d4 * 4);
    const float4 xv = *(const float4*)(x + (size_t)gid * 4);
    *(float4*)(out + (size_t)gid * 4) = q;
    const float dx = q.x - xv.x, dy = q.y - xv.y, dz = q.z - xv.z, dw = q.w - xv.w;
    s += dx * dx + dy * dy + dz * dz + dw * dw;
  }
#pragma unroll
  for (int m = 1; m < 64; m <<= 1) s += __shfl_xor(s, m);
  if ((threadIdx.x & 63) == 0) wsum[threadIdx.x >> 6] = s;
  __syncthreads();
  if (threadIdx.x == 0)
    partials[blockIdx.x] = wsum[0] + wsum[1] + wsum[2] + wsum[3];
}

// ---------------------------------------------------------------------------
// K6: final loss reduce — 1 block, 256 threads over 2048 partials (double).
// ---------------------------------------------------------------------------
__global__ void k_loss(const float* __restrict__ partials, float* __restrict__ loss_cell) {
  __shared__ double wsum[4];
  double s = 0.0;
#pragma unroll
  for (int i = 0; i < 8; ++i) s += (double)partials[i * 256 + threadIdx.x];
#pragma unroll
  for (int m = 1; m < 64; m <<= 1) s += __shfl_xor(s, m);
  if ((threadIdx.x & 63) == 0) wsum[threadIdx.x >> 6] = s;
  __syncthreads();
  if (threadIdx.x == 0)
    *loss_cell = (float)((wsum[0] + wsum[1] + wsum[2] + wsum[3]) *
                         (1.25 / (double)((size_t)NROWS * DIMS)));
}

// ---------------------------------------------------------------------------
extern "C" void kernel_launch(void* const* d_in, const int* in_sizes, int n_in,
                              void* d_out, int out_size, void* d_ws, size_t ws_size,
                              hipStream_t stream) {
  const float* x = (const float*)d_in[0];
  const float* cb = (const float*)d_in[1];
  float* out = (float*)d_out;
  char* ws = (char*)d_ws;

  float* cnorm = (float*)(ws + 0);
  float* d1h = (float*)(ws + 32768);
  float* d2h = (float*)(ws + 294912);
  int* idxh = (int*)(ws + 557056);
  unsigned* bestidx = (unsigned*)(ws + 819200);
  unsigned long long* bestkey = (unsigned long long*)(ws + 950272);
  int* wlist = (int*)(ws + 1212416);
  int* wcount = (int*)(ws + 1343488);
  float* partials = (float*)(ws + 1345536);  // 8 KB
  _Float16* cbh = (_Float16*)(ws + 1376256); // 4 MB, fast path only
  float* loss_cell = out + (NROWS * DIMS);

  const bool fast = ws_size >= (size_t)(1376256 + KCODES * DIMS * 2);

  k_cnorm<<<KCODES / 4, 256, 0, stream>>>(cb, cnorm, wcount, loss_cell);
  if (fast) {
    k_prep<<<KCODES * DIMS / 8 / 256, 256, 0, stream>>>(cb, cbh);
    k_gemm2<<<256, 512, 0, stream>>>(x, cbh, cnorm, d1h, d2h, idxh);
  } else {
    k_gemm<<<256, 512, 0, stream>>>(x, cb, cnorm, d1h, d2h, idxh);
  }
  k_merge<<<NROWS / 256, 256, 0, stream>>>(d1h, d2h, idxh, bestidx, bestkey, wlist, wcount);
  k_refine2<<<KCODES / 32, 512, 0, stream>>>(x, cb, wlist, wcount, bestkey);
  k_out2<<<2048, 256, 0, stream>>>(x, cb, bestidx, bestkey, out, partials);
  k_loss<<<1, 256, 0, stream>>>(partials, loss_cell);
}

// Round 4
// 358.492 us; speedup vs baseline: 3.7871x; 1.1695x over previous
//
#include <hip/hip_runtime.h>
#include <hip/hip_fp16.h>

#define NROWS 32768
#define DIMS 256
#define KCODES 8192
#define MARGIN 0.10f
#define SLACK 0.20f

typedef _Float16 half8 __attribute__((ext_vector_type(8)));
typedef float f32x4 __attribute__((ext_vector_type(4)));

__device__ __forceinline__ void gload_lds16(const void* g, void* l) {
  __builtin_amdgcn_global_load_lds((const __attribute__((address_space(1))) unsigned int*)g,
                                   (__attribute__((address_space(3))) unsigned int*)l, 16, 0, 0);
}

__device__ __forceinline__ unsigned sortable_f32(float f) {
  unsigned u = __float_as_uint(f);
  return u ^ (unsigned)(((int)u >> 31) | 0x80000000);
}

// ---------------------------------------------------------------------------
// K0: fp32 codebook -> f16 codebook (RTN, same numerics as in-register cast).
// ---------------------------------------------------------------------------
__global__ void k_prep(const float* __restrict__ cb, _Float16* __restrict__ cbh) {
  const int g = blockIdx.x * 256 + threadIdx.x;  // 8 floats per thread
  const float4 v0 = *((const float4*)cb + g * 2);
  const float4 v1 = *((const float4*)cb + g * 2 + 1);
  half8 h;
  h[0] = (_Float16)v0.x; h[1] = (_Float16)v0.y;
  h[2] = (_Float16)v0.z; h[3] = (_Float16)v0.w;
  h[4] = (_Float16)v1.x; h[5] = (_Float16)v1.y;
  h[6] = (_Float16)v1.z; h[7] = (_Float16)v1.w;
  *((half8*)cbh + g) = h;
}

// ---------------------------------------------------------------------------
// K1: codebook squared norms; zero worklist counter and loss cell.
// ---------------------------------------------------------------------------
__global__ void k_cnorm(const float* __restrict__ cb, float* __restrict__ cnorm,
                        int* __restrict__ wcount, float* __restrict__ loss_cell) {
  const int lane = threadIdx.x & 63;
  const int code = blockIdx.x * 4 + (threadIdx.x >> 6);
  const float4 v = *((const float4*)(cb + code * DIMS) + lane);
  float s = v.x * v.x + v.y * v.y + v.z * v.z + v.w * v.w;
#pragma unroll
  for (int m = 1; m < 64; m <<= 1) s += __shfl_xor(s, m);
  if (lane == 0) cnorm[code] = s;
  if (blockIdx.x == 0 && threadIdx.x == 0) { *wcount = 0; *loss_cell = 0.0f; }
}

// ---------------------------------------------------------------------------
// K2 (fast): f16 MFMA distance GEMM, f16 codebook staged via global_load_lds
// into double-buffered swizzled LDS (2-way banks = free). One barrier/tile.
// ---------------------------------------------------------------------------
__launch_bounds__(512, 2)
__global__ void k_gemm2(const float* __restrict__ x, const _Float16* __restrict__ cbh,
                        const float* __restrict__ cnorm,
                        float* __restrict__ d1h, float* __restrict__ d2h,
                        int* __restrict__ idxh) {
  __shared__ char B[2][32768];
  const int tid = threadIdx.x;
  const int lane = tid & 63;
  const int w = tid >> 6;
  const int l15 = lane & 15;
  const int lh = lane >> 4;
  const int rowblk = (int)blockIdx.x >> 1;
  const int half = (int)blockIdx.x & 1;
  const int row0 = rowblk * 256 + w * 32;
  const char* cbh_half = (const char*)(cbh + (size_t)half * 4096 * DIMS);

  half8 a[2][8];
#pragma unroll
  for (int m = 0; m < 2; ++m) {
#pragma unroll
    for (int kf = 0; kf < 8; ++kf) {
      const float* s = x + (size_t)(row0 + m * 16 + l15) * DIMS + kf * 32 + lh * 8;
      const float4 v0 = *(const float4*)s;
      const float4 v1 = *(const float4*)(s + 4);
      half8 h;
      h[0] = (_Float16)v0.x; h[1] = (_Float16)v0.y;
      h[2] = (_Float16)v0.z; h[3] = (_Float16)v0.w;
      h[4] = (_Float16)v1.x; h[5] = (_Float16)v1.y;
      h[6] = (_Float16)v1.z; h[7] = (_Float16)v1.w;
      a[m][kf] = h;
    }
  }

  int srcoff[4];
#pragma unroll
  for (int i = 0; i < 4; ++i) {
    const int L = i * 512 + tid;
    const int hi = L >> 6;
    const int lhL = hi & 3, chL = hi >> 2;
    const int code = (L & 63) ^ ((lhL & 1) << 4);
    srcoff[i] = code * 512 + chL * 64 + lhL * 16;
  }

  const int lanebase = l15 * 16 + lh * 1024;
  const int bs = (lh & 1) << 8;
  const int lbp = lanebase + bs;
  const int lbm = lanebase - bs;

  float r1[2][4], r2[2][4];
  int i1[2][4];
#pragma unroll
  for (int m = 0; m < 2; ++m)
#pragma unroll
    for (int j = 0; j < 4; ++j) { r1[m][j] = 3.0e38f; r2[m][j] = 3.0e38f; i1[m][j] = 0; }

  char* lds = &B[0][0];

  auto stage = [&](int t, int bufoff) {
#pragma unroll
    for (int i = 0; i < 4; ++i)
      gload_lds16(cbh_half + t * 32768 + srcoff[i],
                  lds + bufoff + (i * 512 + w * 64) * 16);
  };

  auto compute_tile = [&](int t, int bufoff) {
    const int cbase = half * 4096 + t * 64;
    float cn[4];
#pragma unroll
    for (int n = 0; n < 4; ++n) cn[n] = cnorm[cbase + n * 16 + l15];
    f32x4 acc[2][4];
#pragma unroll
    for (int m = 0; m < 2; ++m)
#pragma unroll
      for (int n = 0; n < 4; ++n) acc[m][n] = (f32x4){0.f, 0.f, 0.f, 0.f};
#pragma unroll
    for (int ch = 0; ch < 8; ++ch) {
      half8 b[4];
#pragma unroll
      for (int n = 0; n < 4; ++n) {
        const int ad = ((n & 1) ? lbm : lbp) + bufoff + ch * 4096 + n * 256;
        b[n] = *(const half8*)(lds + ad);
      }
#pragma unroll
      for (int m = 0; m < 2; ++m)
#pragma unroll
        for (int n = 0; n < 4; ++n)
          acc[m][n] = __builtin_amdgcn_mfma_f32_16x16x32_f16(a[m][ch], b[n], acc[m][n], 0, 0, 0);
    }
#pragma unroll
    for (int m = 0; m < 2; ++m)
#pragma unroll
      for (int n = 0; n < 4; ++n) {
        const int ic = t * 4 + n;
#pragma unroll
        for (int j = 0; j < 4; ++j) {
          const float d = fmaf(-2.0f, acc[m][n][j], cn[n]);
          r2[m][j] = __builtin_amdgcn_fmed3f(d, r1[m][j], r2[m][j]);
          i1[m][j] = (d < r1[m][j]) ? ic : i1[m][j];
          r1[m][j] = fminf(r1[m][j], d);
        }
      }
  };

  stage(0, 0);
#pragma unroll 1
  for (int t = 0; t < 64; t += 2) {
    __syncthreads();
    if (t + 1 < 64) stage(t + 1, 32768);
    compute_tile(t, 0);
    __syncthreads();
    if (t + 2 < 64) stage(t + 2, 0);
    compute_tile(t + 1, 32768);
  }

#pragma unroll
  for (int m = 0; m < 2; ++m)
#pragma unroll
    for (int j = 0; j < 4; ++j) {
      const int code = half * 4096 + (i1[m][j] >> 2) * 64 + (i1[m][j] & 3) * 16 + l15;
      unsigned long long key =
          ((unsigned long long)sortable_f32(r1[m][j]) << 32) | (unsigned)code;
      float t1 = r1[m][j], t2 = r2[m][j];
#pragma unroll
      for (int mk = 1; mk < 16; mk <<= 1) {
        const unsigned long long ok = __shfl_xor(key, mk);
        const float o1 = __shfl_xor(t1, mk);
        const float o2 = __shfl_xor(t2, mk);
        t2 = fminf(fmaxf(t1, o1), fminf(t2, o2));
        t1 = fminf(t1, o1);
        key = (ok < key) ? ok : key;
      }
      if (l15 == 0) {
        const int rg = row0 + m * 16 + lh * 4 + j;
        d1h[half * NROWS + rg] = t1;
        d2h[half * NROWS + rg] = t2;
        idxh[half * NROWS + rg] = (int)(unsigned)(key & 0xffffffffull);
      }
    }
}

// ---------------------------------------------------------------------------
// K2 (fallback, ws too small): converts in-kernel, padded LDS.
// ---------------------------------------------------------------------------
__launch_bounds__(512, 2)
__global__ void k_gemm(const float* __restrict__ x, const float* __restrict__ cb,
                       const float* __restrict__ cnorm,
                       float* __restrict__ d1h, float* __restrict__ d2h,
                       int* __restrict__ idxh) {
  __shared__ _Float16 clds[128][40];
  const int tid = threadIdx.x;
  const int lane = tid & 63;
  const int w = tid >> 6;
  const int l15 = lane & 15;
  const int lh = lane >> 4;
  const int rowblk = (int)blockIdx.x >> 1;
  const int half = (int)blockIdx.x & 1;
  const int row0 = rowblk * 256 + w * 32;

  half8 a[2][8];
#pragma unroll
  for (int m = 0; m < 2; ++m) {
#pragma unroll
    for (int kf = 0; kf < 8; ++kf) {
      const float* s = x + (row0 + m * 16 + l15) * DIMS + kf * 32 + lh * 8;
      const float4 v0 = *(const float4*)s;
      const float4 v1 = *(const float4*)(s + 4);
      half8 h;
      h[0] = (_Float16)v0.x; h[1] = (_Float16)v0.y;
      h[2] = (_Float16)v0.z; h[3] = (_Float16)v0.w;
      h[4] = (_Float16)v1.x; h[5] = (_Float16)v1.y;
      h[6] = (_Float16)v1.z; h[7] = (_Float16)v1.w;
      a[m][kf] = h;
    }
  }

  float r1[2][4], r2[2][4];
  int i1[2][4];
#pragma unroll
  for (int m = 0; m < 2; ++m)
#pragma unroll
    for (int j = 0; j < 4; ++j) { r1[m][j] = 3.0e38f; r2[m][j] = 3.0e38f; i1[m][j] = 0; }

  const int stg_code = tid >> 2;
  const int stg_seg = tid & 3;

  for (int ct = 0; ct < 32; ++ct) {
    const int cbase = half * 4096 + ct * 128;
    f32x4 acc[2][8];
#pragma unroll
    for (int m = 0; m < 2; ++m)
#pragma unroll
      for (int n = 0; n < 8; ++n) acc[m][n] = (f32x4){0.f, 0.f, 0.f, 0.f};

#pragma unroll
    for (int ch = 0; ch < 8; ++ch) {
      __syncthreads();
      {
        const float* s = cb + (cbase + stg_code) * DIMS + ch * 32 + stg_seg * 8;
        const float4 v0 = *(const float4*)s;
        const float4 v1 = *(const float4*)(s + 4);
        half8 h;
        h[0] = (_Float16)v0.x; h[1] = (_Float16)v0.y;
        h[2] = (_Float16)v0.z; h[3] = (_Float16)v0.w;
        h[4] = (_Float16)v1.x; h[5] = (_Float16)v1.y;
        h[6] = (_Float16)v1.z; h[7] = (_Float16)v1.w;
        *(half8*)&clds[stg_code][stg_seg * 8] = h;
      }
      __syncthreads();
      half8 b[8];
#pragma unroll
      for (int n = 0; n < 8; ++n)
        b[n] = *(const half8*)&clds[n * 16 + l15][lh * 8];
#pragma unroll
      for (int m = 0; m < 2; ++m)
#pragma unroll
        for (int n = 0; n < 8; ++n)
          acc[m][n] = __builtin_amdgcn_mfma_f32_16x16x32_f16(a[m][ch], b[n], acc[m][n], 0, 0, 0);
    }

    float cn[8];
#pragma unroll
    for (int n = 0; n < 8; ++n) cn[n] = cnorm[cbase + n * 16 + l15];
#pragma unroll
    for (int m = 0; m < 2; ++m)
#pragma unroll
      for (int n = 0; n < 8; ++n) {
        const int ic = ct * 8 + n;
#pragma unroll
        for (int j = 0; j < 4; ++j) {
          const float d = fmaf(-2.0f, acc[m][n][j], cn[n]);
          r2[m][j] = __builtin_amdgcn_fmed3f(d, r1[m][j], r2[m][j]);
          i1[m][j] = (d < r1[m][j]) ? ic : i1[m][j];
          r1[m][j] = fminf(r1[m][j], d);
        }
      }
  }

#pragma unroll
  for (int m = 0; m < 2; ++m)
#pragma unroll
    for (int j = 0; j < 4; ++j) {
      const int code = half * 4096 + (i1[m][j] >> 3) * 128 + (i1[m][j] & 7) * 16 + l15;
      unsigned long long key =
          ((unsigned long long)sortable_f32(r1[m][j]) << 32) | (unsigned)code;
      float t1 = r1[m][j], t2 = r2[m][j];
#pragma unroll
      for (int mk = 1; mk < 16; mk <<= 1) {
        const unsigned long long ok = __shfl_xor(key, mk);
        const float o1 = __shfl_xor(t1, mk);
        const float o2 = __shfl_xor(t2, mk);
        t2 = fminf(fmaxf(t1, o1), fminf(t2, o2));
        t1 = fminf(t1, o1);
        key = (ok < key) ? ok : key;
      }
      if (l15 == 0) {
        const int rg = row0 + m * 16 + lh * 4 + j;
        d1h[half * NROWS + rg] = t1;
        d2h[half * NROWS + rg] = t2;
        idxh[half * NROWS + rg] = (int)(unsigned)(key & 0xffffffffull);
      }
    }
}

// ---------------------------------------------------------------------------
// K3: merge halves + compute ||x||^2 + flag near-ties. bestkey for flagged
// rows is initialized to the approx-best TRUE distance + SLACK so refinement
// gates work on a consistent scale. 512 blocks x 256 thr, 64 rows/block.
// ---------------------------------------------------------------------------
__global__ void k_merge(const float* __restrict__ x,
                        const float* __restrict__ d1h, const float* __restrict__ d2h,
                        const int* __restrict__ idxh, unsigned* __restrict__ bestidx,
                        unsigned long long* __restrict__ bestkey,
                        int* __restrict__ wlist, int* __restrict__ wcount) {
  const int t = threadIdx.x;
  const int lane = t & 63;
  const int r = blockIdx.x * 64 + (t >> 2);
  const int q = t & 3;
  const float4* xr = (const float4*)(x + (size_t)r * DIMS) + q * 16;
  float xn = 0.f;
#pragma unroll
  for (int i = 0; i < 16; ++i) {
    const float4 v = xr[i];
    xn += v.x * v.x + v.y * v.y + v.z * v.z + v.w * v.w;
  }
  xn += __shfl_xor(xn, 1);
  xn += __shfl_xor(xn, 2);

  bool flag = false;
  float lo = 0.f;
  int idx = 0;
  if (q == 0) {
    const float a1 = d1h[r], b1 = d1h[NROWS + r];
    const float a2 = d2h[r], b2 = d2h[NROWS + r];
    const int ia = idxh[r], ib = idxh[NROWS + r];
    lo = fminf(a1, b1);
    const float hi = fmaxf(a1, b1);
    const float d2 = fminf(hi, fminf(a2, b2));
    idx = (b1 < a1) ? ib : ia;
    flag = (d2 - lo) < MARGIN;
    bestidx[r] = (unsigned)idx | (flag ? 0x80000000u : 0u);
    if (flag)
      bestkey[r] = ((unsigned long long)__float_as_uint(lo + xn + SLACK) << 32) |
                   (unsigned)idx;
  }
  // wave-aggregated worklist append
  const unsigned long long m = __ballot(flag);
  const int cnt = __popcll(m);
  int base = 0;
  if (lane == 0 && cnt) base = atomicAdd(wcount, cnt);
  base = __shfl(base, 0);
  if (flag) {
    const int pre = __popcll(m & ((1ull << lane) - 1ull));
    wlist[base + pre] = r;
  }
}

// ---------------------------------------------------------------------------
// K4: exact refinement v3. Block b owns codes [b*32,b*32+32) held in
// REGISTERS (16 floats/thread: ci=tid>>4, piece=tid&15). Rows staged in
// chunks of 8 into double-buffered LDS (2 barriers per 8 rows). Per row:
// 16 FMA + 4-shfl piece reduce + packed (dist,code) key + 2 key-min shfl.
// Per chunk: lane0 batches 8 gate loads then read-gated atomicMin.
// ---------------------------------------------------------------------------
__launch_bounds__(512, 1)
__global__ void k_refine3(const float* __restrict__ x, const float* __restrict__ cb,
                          const int* __restrict__ wlist, const int* __restrict__ wcount,
                          unsigned long long* __restrict__ bestkey) {
  __shared__ float xl[2][8][272];
  __shared__ int rl[2][8];
  const int tid = threadIdx.x;
  const int lane = tid & 63;
  const int ci = tid >> 4;     // 0..31
  const int piece = tid & 15;  // 0..15
  const int codeg = blockIdx.x * 32 + ci;

  float cr[16];
  {
    const float4* cp = (const float4*)(cb + (size_t)codeg * DIMS + piece * 16);
#pragma unroll
    for (int i = 0; i < 4; ++i) {
      const float4 v = cp[i];
      cr[i * 4 + 0] = v.x; cr[i * 4 + 1] = v.y;
      cr[i * 4 + 2] = v.z; cr[i * 4 + 3] = v.w;
    }
  }

  const int nf = *wcount;
  if (nf == 0) return;
  const int nc = (nf + 7) >> 3;                       // chunks of 8 rows
  const int startc = (int)(((long long)blockIdx.x * nc) >> 8);

  const int slot = tid >> 6;       // 0..7 (wave id = row slot for staging)
  const int dlane = tid & 63;

  auto stage = [&](int c, int buf) {
    int chunkid = startc + c;
    if (chunkid >= nc) chunkid -= nc;
    int ridx = chunkid * 8 + slot;
    if (ridx >= nf) ridx %= nf;  // wraparound duplicates are harmless
    const int row = wlist[ridx];
    if (dlane == 0) rl[buf][slot] = row;
    const float4* xs = (const float4*)(x + (size_t)row * DIMS) + dlane;
    *(float4*)&xl[buf][slot][dlane * 4] = *xs;
  };

  stage(0, 0);
#pragma unroll 1
  for (int c = 0; c < nc; ++c) {
    const int buf = c & 1;
    __syncthreads();
    if (c + 1 < nc) stage(c + 1, buf ^ 1);

    unsigned long long k[8];
#pragma unroll
    for (int r = 0; r < 8; ++r) {
      const float* xr = &xl[buf][r][piece * 16];
      const float4 a0 = *(const float4*)(xr + 0);
      const float4 a1 = *(const float4*)(xr + 4);
      const float4 a2 = *(const float4*)(xr + 8);
      const float4 a3 = *(const float4*)(xr + 12);
      float s0, s1, s2, s3;
      {
        float d;
        d = a0.x - cr[0];  s0 = d * d;
        d = a0.y - cr[1];  s0 = fmaf(d, d, s0);
        d = a0.z - cr[2];  s0 = fmaf(d, d, s0);
        d = a0.w - cr[3];  s0 = fmaf(d, d, s0);
        d = a1.x - cr[4];  s1 = d * d;
        d = a1.y - cr[5];  s1 = fmaf(d, d, s1);
        d = a1.z - cr[6];  s1 = fmaf(d, d, s1);
        d = a1.w - cr[7];  s1 = fmaf(d, d, s1);
        d = a2.x - cr[8];  s2 = d * d;
        d = a2.y - cr[9];  s2 = fmaf(d, d, s2);
        d = a2.z - cr[10]; s2 = fmaf(d, d, s2);
        d = a2.w - cr[11]; s2 = fmaf(d, d, s2);
        d = a3.x - cr[12]; s3 = d * d;
        d = a3.y - cr[13]; s3 = fmaf(d, d, s3);
        d = a3.z - cr[14]; s3 = fmaf(d, d, s3);
        d = a3.w - cr[15]; s3 = fmaf(d, d, s3);
      }
      float s = (s0 + s1) + (s2 + s3);
      s += __shfl_xor(s, 1);
      s += __shfl_xor(s, 2);
      s += __shfl_xor(s, 4);
      s += __shfl_xor(s, 8);
      unsigned long long key =
          ((unsigned long long)__float_as_uint(s) << 32) | (unsigned)codeg;
      unsigned long long ok = __shfl_xor(key, 16);
      key = (ok < key) ? ok : key;
      ok = __shfl_xor(key, 32);
      key = (ok < key) ? ok : key;
      k[r] = key;
    }

    if (lane == 0) {
      int rows[8];
      unsigned long long cur[8];
#pragma unroll
      for (int r = 0; r < 8; ++r) rows[r] = rl[buf][r];
#pragma unroll
      for (int r = 0; r < 8; ++r) cur[r] = bestkey[rows[r]];
#pragma unroll
      for (int r = 0; r < 8; ++r)
        if (k[r] < cur[r]) atomicMin(&bestkey[rows[r]], k[r]);
    }
  }
}

// ---------------------------------------------------------------------------
// K5: gather quantized output + per-block loss partials (NO global atomics).
// ---------------------------------------------------------------------------
__launch_bounds__(256)
__global__ void k_out2(const float* __restrict__ x, const float* __restrict__ cb,
                       const unsigned* __restrict__ bestidx,
                       const unsigned long long* __restrict__ bestkey,
                       float* __restrict__ out, float* __restrict__ partials) {
  __shared__ float wsum[4];
  float s = 0.f;
#pragma unroll
  for (int it = 0; it < 4; ++it) {
    const int gid = (it * 2048 + blockIdx.x) * 256 + threadIdx.x;
    const int row = gid >> 6, d4 = gid & 63;
    const unsigned bi = bestidx[row];
    unsigned idx = bi & 0x7fffffffu;
    if (bi >> 31) idx = (unsigned)(bestkey[row] & 0xffffffffull);
    const float4 q = *(const float4*)(cb + (size_t)idx * DIMS + d4 * 4);
    const float4 xv = *(const float4*)(x + (size_t)gid * 4);
    *(float4*)(out + (size_t)gid * 4) = q;
    const float dx = q.x - xv.x, dy = q.y - xv.y, dz = q.z - xv.z, dw = q.w - xv.w;
    s += dx * dx + dy * dy + dz * dz + dw * dw;
  }
#pragma unroll
  for (int m = 1; m < 64; m <<= 1) s += __shfl_xor(s, m);
  if ((threadIdx.x & 63) == 0) wsum[threadIdx.x >> 6] = s;
  __syncthreads();
  if (threadIdx.x == 0)
    partials[blockIdx.x] = wsum[0] + wsum[1] + wsum[2] + wsum[3];
}

// ---------------------------------------------------------------------------
// K6: final loss reduce — 1 block, 256 threads over 2048 partials (double).
// ---------------------------------------------------------------------------
__global__ void k_loss(const float* __restrict__ partials, float* __restrict__ loss_cell) {
  __shared__ double wsum[4];
  double s = 0.0;
#pragma unroll
  for (int i = 0; i < 8; ++i) s += (double)partials[i * 256 + threadIdx.x];
#pragma unroll
  for (int m = 1; m < 64; m <<= 1) s += __shfl_xor(s, m);
  if ((threadIdx.x & 63) == 0) wsum[threadIdx.x >> 6] = s;
  __syncthreads();
  if (threadIdx.x == 0)
    *loss_cell = (float)((wsum[0] + wsum[1] + wsum[2] + wsum[3]) *
                         (1.25 / (double)((size_t)NROWS * DIMS)));
}

// ---------------------------------------------------------------------------
extern "C" void kernel_launch(void* const* d_in, const int* in_sizes, int n_in,
                              void* d_out, int out_size, void* d_ws, size_t ws_size,
                              hipStream_t stream) {
  const float* x = (const float*)d_in[0];
  const float* cb = (const float*)d_in[1];
  float* out = (float*)d_out;
  char* ws = (char*)d_ws;

  float* cnorm = (float*)(ws + 0);
  float* d1h = (float*)(ws + 32768);
  float* d2h = (float*)(ws + 294912);
  int* idxh = (int*)(ws + 557056);
  unsigned* bestidx = (unsigned*)(ws + 819200);
  unsigned long long* bestkey = (unsigned long long*)(ws + 950272);
  int* wlist = (int*)(ws + 1212416);
  int* wcount = (int*)(ws + 1343488);
  float* partials = (float*)(ws + 1345536);
  _Float16* cbh = (_Float16*)(ws + 1376256);
  float* loss_cell = out + (NROWS * DIMS);

  const bool fast = ws_size >= (size_t)(1376256 + KCODES * DIMS * 2);

  k_cnorm<<<KCODES / 4, 256, 0, stream>>>(cb, cnorm, wcount, loss_cell);
  if (fast) {
    k_prep<<<KCODES * DIMS / 8 / 256, 256, 0, stream>>>(cb, cbh);
    k_gemm2<<<256, 512, 0, stream>>>(x, cbh, cnorm, d1h, d2h, idxh);
  } else {
    k_gemm<<<256, 512, 0, stream>>>(x, cb, cnorm, d1h, d2h, idxh);
  }
  k_merge<<<NROWS / 64, 256, 0, stream>>>(x, d1h, d2h, idxh, bestidx, bestkey, wlist, wcount);
  k_refine3<<<KCODES / 32, 512, 0, stream>>>(x, cb, wlist, wcount, bestkey);
  k_out2<<<2048, 256, 0, stream>>>(x, cb, bestidx, bestkey, out, partials);
  k_loss<<<1, 256, 0, stream>>>(partials, loss_cell);
}

// Round 5
// 334.415 us; speedup vs baseline: 4.0598x; 1.0720x over previous
//
#include <hip/hip_runtime.h>
#include <hip/hip_fp16.h>

#define NROWS 32768
#define DIMS 256
#define KCODES 8192
#define MARGIN 0.10f

typedef _Float16 half8 __attribute__((ext_vector_type(8)));
typedef float f32x4 __attribute__((ext_vector_type(4)));
typedef unsigned long long u64;

__device__ __forceinline__ void gload_lds16(const void* g, void* l) {
  __builtin_amdgcn_global_load_lds((const __attribute__((address_space(1))) unsigned int*)g,
                                   (__attribute__((address_space(3))) unsigned int*)l, 16, 0, 0);
}

__device__ __forceinline__ unsigned sortable_f32(float f) {
  unsigned u = __float_as_uint(f);
  return u ^ (unsigned)(((int)u >> 31) | 0x80000000);
}
__device__ __forceinline__ float unsortable_f32(unsigned s) {
  const unsigned m = ((int)s < 0) ? 0x80000000u : 0xFFFFFFFFu;
  return __uint_as_float(s ^ m);
}
__device__ __forceinline__ u64 umin64(u64 a, u64 b) { return a < b ? a : b; }
__device__ __forceinline__ u64 umax64(u64 a, u64 b) { return a > b ? a : b; }

// ---------------------------------------------------------------------------
// K0: fp32 codebook -> f16 codebook (RTN, same numerics as in-register cast).
// ---------------------------------------------------------------------------
__global__ void k_prep(const float* __restrict__ cb, _Float16* __restrict__ cbh) {
  const int g = blockIdx.x * 256 + threadIdx.x;
  const float4 v0 = *((const float4*)cb + g * 2);
  const float4 v1 = *((const float4*)cb + g * 2 + 1);
  half8 h;
  h[0] = (_Float16)v0.x; h[1] = (_Float16)v0.y;
  h[2] = (_Float16)v0.z; h[3] = (_Float16)v0.w;
  h[4] = (_Float16)v1.x; h[5] = (_Float16)v1.y;
  h[6] = (_Float16)v1.z; h[7] = (_Float16)v1.w;
  *((half8*)cbh + g) = h;
}

// ---------------------------------------------------------------------------
// K1: codebook squared norms; zero counters and loss cell.
// ---------------------------------------------------------------------------
__global__ void k_cnorm(const float* __restrict__ cb, float* __restrict__ cnorm,
                        int* __restrict__ wcount, int* __restrict__ scount,
                        float* __restrict__ loss_cell) {
  const int lane = threadIdx.x & 63;
  const int code = blockIdx.x * 4 + (threadIdx.x >> 6);
  const float4 v = *((const float4*)(cb + code * DIMS) + lane);
  float s = v.x * v.x + v.y * v.y + v.z * v.z + v.w * v.w;
#pragma unroll
  for (int m = 1; m < 64; m <<= 1) s += __shfl_xor(s, m);
  if (lane == 0) cnorm[code] = s;
  if (blockIdx.x == 0 && threadIdx.x == 0) {
    *wcount = 0; *scount = 0; *loss_cell = 0.0f;
  }
}

// ---------------------------------------------------------------------------
// K2 (fast): f16 MFMA distance GEMM. Tracks per-row running top-3 values +
// top-2 indices in-lane; one cross-lane packed-key sorted-merge at the end.
// Outputs per row-half: pk1,pk2 (packed (sortable_dist,code) u64), d3 (f32).
// ---------------------------------------------------------------------------
__launch_bounds__(512, 2)
__global__ void k_gemm2(const float* __restrict__ x, const _Float16* __restrict__ cbh,
                        const float* __restrict__ cnorm,
                        u64* __restrict__ pk1, u64* __restrict__ pk2,
                        float* __restrict__ d3h) {
  __shared__ char B[2][32768];
  const int tid = threadIdx.x;
  const int lane = tid & 63;
  const int w = tid >> 6;
  const int l15 = lane & 15;
  const int lh = lane >> 4;
  const int rowblk = (int)blockIdx.x >> 1;
  const int half = (int)blockIdx.x & 1;
  const int row0 = rowblk * 256 + w * 32;
  const char* cbh_half = (const char*)(cbh + (size_t)half * 4096 * DIMS);

  half8 a[2][8];
#pragma unroll
  for (int m = 0; m < 2; ++m) {
#pragma unroll
    for (int kf = 0; kf < 8; ++kf) {
      const float* s = x + (size_t)(row0 + m * 16 + l15) * DIMS + kf * 32 + lh * 8;
      const float4 v0 = *(const float4*)s;
      const float4 v1 = *(const float4*)(s + 4);
      half8 h;
      h[0] = (_Float16)v0.x; h[1] = (_Float16)v0.y;
      h[2] = (_Float16)v0.z; h[3] = (_Float16)v0.w;
      h[4] = (_Float16)v1.x; h[5] = (_Float16)v1.y;
      h[6] = (_Float16)v1.z; h[7] = (_Float16)v1.w;
      a[m][kf] = h;
    }
  }

  int srcoff[4];
#pragma unroll
  for (int i = 0; i < 4; ++i) {
    const int L = i * 512 + tid;
    const int hi = L >> 6;
    const int lhL = hi & 3, chL = hi >> 2;
    const int code = (L & 63) ^ ((lhL & 1) << 4);
    srcoff[i] = code * 512 + chL * 64 + lhL * 16;
  }

  const int lanebase = l15 * 16 + lh * 1024;
  const int bs = (lh & 1) << 8;
  const int lbp = lanebase + bs;
  const int lbm = lanebase - bs;

  float r1[2][4], r2[2][4], r3[2][4];
  int i1[2][4], i2[2][4];
#pragma unroll
  for (int m = 0; m < 2; ++m)
#pragma unroll
    for (int j = 0; j < 4; ++j) {
      r1[m][j] = 3.0e38f; r2[m][j] = 3.0e38f; r3[m][j] = 3.0e38f;
      i1[m][j] = 0; i2[m][j] = 0;
    }

  char* lds = &B[0][0];

  auto stage = [&](int t, int bufoff) {
#pragma unroll
    for (int i = 0; i < 4; ++i)
      gload_lds16(cbh_half + t * 32768 + srcoff[i],
                  lds + bufoff + (i * 512 + w * 64) * 16);
  };

  auto compute_tile = [&](int t, int bufoff) {
    const int cbase = half * 4096 + t * 64;
    float cn[4];
#pragma unroll
    for (int n = 0; n < 4; ++n) cn[n] = cnorm[cbase + n * 16 + l15];
    f32x4 acc[2][4];
#pragma unroll
    for (int m = 0; m < 2; ++m)
#pragma unroll
      for (int n = 0; n < 4; ++n) acc[m][n] = (f32x4){0.f, 0.f, 0.f, 0.f};
#pragma unroll
    for (int ch = 0; ch < 8; ++ch) {
      half8 b[4];
#pragma unroll
      for (int n = 0; n < 4; ++n) {
        const int ad = ((n & 1) ? lbm : lbp) + bufoff + ch * 4096 + n * 256;
        b[n] = *(const half8*)(lds + ad);
      }
#pragma unroll
      for (int m = 0; m < 2; ++m)
#pragma unroll
        for (int n = 0; n < 4; ++n)
          acc[m][n] = __builtin_amdgcn_mfma_f32_16x16x32_f16(a[m][ch], b[n], acc[m][n], 0, 0, 0);
    }
#pragma unroll
    for (int m = 0; m < 2; ++m)
#pragma unroll
      for (int n = 0; n < 4; ++n) {
        const int ic = t * 4 + n;
#pragma unroll
        for (int j = 0; j < 4; ++j) {
          const float d = fmaf(-2.0f, acc[m][n][j], cn[n]);
          const bool lt1 = d < r1[m][j];
          const bool lt2 = d < r2[m][j];
          r3[m][j] = __builtin_amdgcn_fmed3f(d, r2[m][j], r3[m][j]);
          i2[m][j] = lt2 ? (lt1 ? i1[m][j] : ic) : i2[m][j];
          r2[m][j] = __builtin_amdgcn_fmed3f(d, r1[m][j], r2[m][j]);
          i1[m][j] = lt1 ? ic : i1[m][j];
          r1[m][j] = fminf(d, r1[m][j]);
        }
      }
  };

  stage(0, 0);
#pragma unroll 1
  for (int t = 0; t < 64; t += 2) {
    __syncthreads();
    if (t + 1 < 64) stage(t + 1, 32768);
    compute_tile(t, 0);
    __syncthreads();
    if (t + 2 < 64) stage(t + 2, 0);
    compute_tile(t + 1, 32768);
  }

  // Cross-lane sorted-merge of per-lane top-3 (packed u64 keys).
#pragma unroll
  for (int m = 0; m < 2; ++m)
#pragma unroll
    for (int j = 0; j < 4; ++j) {
      const int ia = i1[m][j], ib = i2[m][j];
      const unsigned c1 = half * 4096 + (ia >> 2) * 64 + (ia & 3) * 16 + l15;
      const unsigned c2 = half * 4096 + (ib >> 2) * 64 + (ib & 3) * 16 + l15;
      u64 k1 = ((u64)sortable_f32(r1[m][j]) << 32) | c1;
      u64 k2 = ((u64)sortable_f32(r2[m][j]) << 32) | c2;
      u64 k3 = ((u64)sortable_f32(r3[m][j]) << 32);
#pragma unroll
      for (int mk = 1; mk < 16; mk <<= 1) {
        const u64 o1 = __shfl_xor(k1, mk);
        const u64 o2 = __shfl_xor(k2, mk);
        const u64 o3 = __shfl_xor(k3, mk);
        const u64 hi1 = umax64(k1, o1);
        k3 = umin64(umin64(k3, o3), umin64(umax64(k1, o2), umax64(k2, o1)));
        k2 = umin64(hi1, umin64(k2, o2));
        k1 = umin64(k1, o1);
      }
      if (l15 == 0) {
        const int rg = row0 + m * 16 + lh * 4 + j;
        pk1[half * NROWS + rg] = k1;
        pk2[half * NROWS + rg] = k2;
        d3h[half * NROWS + rg] = unsortable_f32((unsigned)(k3 >> 32));
      }
    }
}

// ---------------------------------------------------------------------------
// K2 (fallback, ws too small): converts in-kernel, padded LDS. Same outputs.
// ---------------------------------------------------------------------------
__launch_bounds__(512, 2)
__global__ void k_gemm(const float* __restrict__ x, const float* __restrict__ cb,
                       const float* __restrict__ cnorm,
                       u64* __restrict__ pk1, u64* __restrict__ pk2,
                       float* __restrict__ d3h) {
  __shared__ _Float16 clds[128][40];
  const int tid = threadIdx.x;
  const int lane = tid & 63;
  const int w = tid >> 6;
  const int l15 = lane & 15;
  const int lh = lane >> 4;
  const int rowblk = (int)blockIdx.x >> 1;
  const int half = (int)blockIdx.x & 1;
  const int row0 = rowblk * 256 + w * 32;

  half8 a[2][8];
#pragma unroll
  for (int m = 0; m < 2; ++m) {
#pragma unroll
    for (int kf = 0; kf < 8; ++kf) {
      const float* s = x + (row0 + m * 16 + l15) * DIMS + kf * 32 + lh * 8;
      const float4 v0 = *(const float4*)s;
      const float4 v1 = *(const float4*)(s + 4);
      half8 h;
      h[0] = (_Float16)v0.x; h[1] = (_Float16)v0.y;
      h[2] = (_Float16)v0.z; h[3] = (_Float16)v0.w;
      h[4] = (_Float16)v1.x; h[5] = (_Float16)v1.y;
      h[6] = (_Float16)v1.z; h[7] = (_Float16)v1.w;
      a[m][kf] = h;
    }
  }

  float r1[2][4], r2[2][4], r3[2][4];
  int i1[2][4], i2[2][4];
#pragma unroll
  for (int m = 0; m < 2; ++m)
#pragma unroll
    for (int j = 0; j < 4; ++j) {
      r1[m][j] = 3.0e38f; r2[m][j] = 3.0e38f; r3[m][j] = 3.0e38f;
      i1[m][j] = 0; i2[m][j] = 0;
    }

  const int stg_code = tid >> 2;
  const int stg_seg = tid & 3;

  for (int ct = 0; ct < 32; ++ct) {
    const int cbase = half * 4096 + ct * 128;
    f32x4 acc[2][8];
#pragma unroll
    for (int m = 0; m < 2; ++m)
#pragma unroll
      for (int n = 0; n < 8; ++n) acc[m][n] = (f32x4){0.f, 0.f, 0.f, 0.f};

#pragma unroll
    for (int ch = 0; ch < 8; ++ch) {
      __syncthreads();
      {
        const float* s = cb + (cbase + stg_code) * DIMS + ch * 32 + stg_seg * 8;
        const float4 v0 = *(const float4*)s;
        const float4 v1 = *(const float4*)(s + 4);
        half8 h;
        h[0] = (_Float16)v0.x; h[1] = (_Float16)v0.y;
        h[2] = (_Float16)v0.z; h[3] = (_Float16)v0.w;
        h[4] = (_Float16)v1.x; h[5] = (_Float16)v1.y;
        h[6] = (_Float16)v1.z; h[7] = (_Float16)v1.w;
        *(half8*)&clds[stg_code][stg_seg * 8] = h;
      }
      __syncthreads();
      half8 b[8];
#pragma unroll
      for (int n = 0; n < 8; ++n)
        b[n] = *(const half8*)&clds[n * 16 + l15][lh * 8];
#pragma unroll
      for (int m = 0; m < 2; ++m)
#pragma unroll
        for (int n = 0; n < 8; ++n)
          acc[m][n] = __builtin_amdgcn_mfma_f32_16x16x32_f16(a[m][ch], b[n], acc[m][n], 0, 0, 0);
    }

    float cn[8];
#pragma unroll
    for (int n = 0; n < 8; ++n) cn[n] = cnorm[cbase + n * 16 + l15];
#pragma unroll
    for (int m = 0; m < 2; ++m)
#pragma unroll
      for (int n = 0; n < 8; ++n) {
        const int ic = ct * 8 + n;
#pragma unroll
        for (int j = 0; j < 4; ++j) {
          const float d = fmaf(-2.0f, acc[m][n][j], cn[n]);
          const bool lt1 = d < r1[m][j];
          const bool lt2 = d < r2[m][j];
          r3[m][j] = __builtin_amdgcn_fmed3f(d, r2[m][j], r3[m][j]);
          i2[m][j] = lt2 ? (lt1 ? i1[m][j] : ic) : i2[m][j];
          r2[m][j] = __builtin_amdgcn_fmed3f(d, r1[m][j], r2[m][j]);
          i1[m][j] = lt1 ? ic : i1[m][j];
          r1[m][j] = fminf(d, r1[m][j]);
        }
      }
  }

#pragma unroll
  for (int m = 0; m < 2; ++m)
#pragma unroll
    for (int j = 0; j < 4; ++j) {
      const int ia = i1[m][j], ib = i2[m][j];
      const unsigned c1 = half * 4096 + (ia >> 3) * 128 + (ia & 7) * 16 + l15;
      const unsigned c2 = half * 4096 + (ib >> 3) * 128 + (ib & 7) * 16 + l15;
      u64 k1 = ((u64)sortable_f32(r1[m][j]) << 32) | c1;
      u64 k2 = ((u64)sortable_f32(r2[m][j]) << 32) | c2;
      u64 k3 = ((u64)sortable_f32(r3[m][j]) << 32);
#pragma unroll
      for (int mk = 1; mk < 16; mk <<= 1) {
        const u64 o1 = __shfl_xor(k1, mk);
        const u64 o2 = __shfl_xor(k2, mk);
        const u64 o3 = __shfl_xor(k3, mk);
        const u64 hi1 = umax64(k1, o1);
        k3 = umin64(umin64(k3, o3), umin64(umax64(k1, o2), umax64(k2, o1)));
        k2 = umin64(hi1, umin64(k2, o2));
        k1 = umin64(k1, o1);
      }
      if (l15 == 0) {
        const int rg = row0 + m * 16 + lh * 4 + j;
        pk1[half * NROWS + rg] = k1;
        pk2[half * NROWS + rg] = k2;
        d3h[half * NROWS + rg] = unsortable_f32((unsigned)(k3 >> 32));
      }
    }
}

// ---------------------------------------------------------------------------
// K3: merge halves; classify rows: clean / soft (2-candidate) / hard (full).
// ---------------------------------------------------------------------------
__global__ void k_merge(const u64* __restrict__ pk1, const u64* __restrict__ pk2,
                        const float* __restrict__ d3h,
                        unsigned* __restrict__ bestidx, u64* __restrict__ bestkey,
                        int* __restrict__ wlist, int* __restrict__ wcount,
                        int* __restrict__ slist, int* __restrict__ scount) {
  const int r = blockIdx.x * 256 + threadIdx.x;
  const int lane = threadIdx.x & 63;
  const u64 k1a = pk1[r], k1b = pk1[NROWS + r];
  const u64 k2a = pk2[r], k2b = pk2[NROWS + r];
  const float d3a = d3h[r], d3b = d3h[NROWS + r];
  const u64 K1 = umin64(k1a, k1b);
  const u64 K2 = umin64(umax64(k1a, k1b), umin64(k2a, k2b));
  const u64 cross = umin64(umax64(k1a, k2b), umax64(k2a, k1b));
  const float d3 = fminf(fminf(d3a, d3b), unsortable_f32((unsigned)(cross >> 32)));
  const float d1 = unsortable_f32((unsigned)(K1 >> 32));
  const float d2 = unsortable_f32((unsigned)(K2 >> 32));
  const bool hard = (d3 - d1) < MARGIN;
  const bool soft = !hard && ((d2 - d1) < MARGIN);
  bestidx[r] = (unsigned)(K1 & 0xffffffffull) | (hard ? 0x80000000u : 0u);
  if (hard) bestkey[r] = ~0ull;
  {
    const u64 mb = __ballot(hard);
    const int cnt = __popcll(mb);
    int base = 0;
    if (lane == 0 && cnt) base = atomicAdd(wcount, cnt);
    base = __shfl(base, 0);
    if (hard) wlist[base + __popcll(mb & ((1ull << lane) - 1ull))] = r;
  }
  {
    const u64 mb = __ballot(soft);
    const int cnt = __popcll(mb);
    int base = 0;
    if (lane == 0 && cnt) base = atomicAdd(scount, cnt);
    base = __shfl(base, 0);
    if (soft) slist[base + __popcll(mb & ((1ull << lane) - 1ull))] = r;
  }
}

// ---------------------------------------------------------------------------
// K4a: soft rows — exact 2-candidate compare. One wave per row.
// Writes resolved bestidx directly (clears any ambiguity without bestkey).
// ---------------------------------------------------------------------------
__launch_bounds__(256)
__global__ void k_soft(const float* __restrict__ x, const float* __restrict__ cb,
                       const u64* __restrict__ pk1, const u64* __restrict__ pk2,
                       const int* __restrict__ slist, const int* __restrict__ scount,
                       unsigned* __restrict__ bestidx) {
  const int tid = threadIdx.x;
  const int lane = tid & 63;
  const int gw = blockIdx.x * 4 + (tid >> 6);
  const int ns = *scount;
  for (int i = gw; i < ns; i += 256) {
    const int r = slist[i];
    const u64 k1a = pk1[r], k1b = pk1[NROWS + r];
    const u64 k2a = pk2[r], k2b = pk2[NROWS + r];
    const u64 K1 = umin64(k1a, k1b);
    const u64 K2 = umin64(umax64(k1a, k1b), umin64(k2a, k2b));
    const unsigned c1 = (unsigned)(K1 & 0xffffffffull);
    const unsigned c2 = (unsigned)(K2 & 0xffffffffull);
    const float4 xv = *((const float4*)(x + (size_t)r * DIMS) + lane);
    const float4 a = *((const float4*)(cb + (size_t)c1 * DIMS) + lane);
    const float4 b = *((const float4*)(cb + (size_t)c2 * DIMS) + lane);
    float e, p1, p2;
    e = xv.x - a.x; p1 = e * e;
    e = xv.y - a.y; p1 = fmaf(e, e, p1);
    e = xv.z - a.z; p1 = fmaf(e, e, p1);
    e = xv.w - a.w; p1 = fmaf(e, e, p1);
    e = xv.x - b.x; p2 = e * e;
    e = xv.y - b.y; p2 = fmaf(e, e, p2);
    e = xv.z - b.z; p2 = fmaf(e, e, p2);
    e = xv.w - b.w; p2 = fmaf(e, e, p2);
    double s1 = (double)p1, s2 = (double)p2;
#pragma unroll
    for (int mk = 1; mk < 64; mk <<= 1) {
      s1 += __shfl_xor(s1, mk);
      s2 += __shfl_xor(s2, mk);
    }
    unsigned win = (s1 < s2) ? c1 : ((s2 < s1) ? c2 : min(c1, c2));
    if (lane == 0) bestidx[r] = win;
  }
}

// ---------------------------------------------------------------------------
// K4b: hard rows — full exact scan (codes in registers, rows via dbuf LDS).
// ---------------------------------------------------------------------------
__launch_bounds__(512, 1)
__global__ void k_refine3(const float* __restrict__ x, const float* __restrict__ cb,
                          const int* __restrict__ wlist, const int* __restrict__ wcount,
                          u64* __restrict__ bestkey) {
  __shared__ float xl[2][8][272];
  __shared__ int rl[2][8];
  const int tid = threadIdx.x;
  const int lane = tid & 63;
  const int ci = tid >> 4;
  const int piece = tid & 15;
  const int codeg = blockIdx.x * 32 + ci;

  float cr[16];
  {
    const float4* cp = (const float4*)(cb + (size_t)codeg * DIMS + piece * 16);
#pragma unroll
    for (int i = 0; i < 4; ++i) {
      const float4 v = cp[i];
      cr[i * 4 + 0] = v.x; cr[i * 4 + 1] = v.y;
      cr[i * 4 + 2] = v.z; cr[i * 4 + 3] = v.w;
    }
  }

  const int nf = *wcount;
  if (nf == 0) return;
  const int nc = (nf + 7) >> 3;
  const int startc = (int)(((long long)blockIdx.x * nc) >> 8);

  const int slot = tid >> 6;
  const int dlane = tid & 63;

  auto stage = [&](int c, int buf) {
    int chunkid = startc + c;
    if (chunkid >= nc) chunkid -= nc;
    int ridx = chunkid * 8 + slot;
    if (ridx >= nf) ridx %= nf;
    const int row = wlist[ridx];
    if (dlane == 0) rl[buf][slot] = row;
    const float4* xs = (const float4*)(x + (size_t)row * DIMS) + dlane;
    *(float4*)&xl[buf][slot][dlane * 4] = *xs;
  };

  stage(0, 0);
#pragma unroll 1
  for (int c = 0; c < nc; ++c) {
    const int buf = c & 1;
    __syncthreads();
    if (c + 1 < nc) stage(c + 1, buf ^ 1);

    u64 k[8];
#pragma unroll
    for (int r = 0; r < 8; ++r) {
      const float* xr = &xl[buf][r][piece * 16];
      const float4 a0 = *(const float4*)(xr + 0);
      const float4 a1 = *(const float4*)(xr + 4);
      const float4 a2 = *(const float4*)(xr + 8);
      const float4 a3 = *(const float4*)(xr + 12);
      float s0, s1, s2, s3;
      {
        float d;
        d = a0.x - cr[0];  s0 = d * d;
        d = a0.y - cr[1];  s0 = fmaf(d, d, s0);
        d = a0.z - cr[2];  s0 = fmaf(d, d, s0);
        d = a0.w - cr[3];  s0 = fmaf(d, d, s0);
        d = a1.x - cr[4];  s1 = d * d;
        d = a1.y - cr[5];  s1 = fmaf(d, d, s1);
        d = a1.z - cr[6];  s1 = fmaf(d, d, s1);
        d = a1.w - cr[7];  s1 = fmaf(d, d, s1);
        d = a2.x - cr[8];  s2 = d * d;
        d = a2.y - cr[9];  s2 = fmaf(d, d, s2);
        d = a2.z - cr[10]; s2 = fmaf(d, d, s2);
        d = a2.w - cr[11]; s2 = fmaf(d, d, s2);
        d = a3.x - cr[12]; s3 = d * d;
        d = a3.y - cr[13]; s3 = fmaf(d, d, s3);
        d = a3.z - cr[14]; s3 = fmaf(d, d, s3);
        d = a3.w - cr[15]; s3 = fmaf(d, d, s3);
      }
      float s = (s0 + s1) + (s2 + s3);
      s += __shfl_xor(s, 1);
      s += __shfl_xor(s, 2);
      s += __shfl_xor(s, 4);
      s += __shfl_xor(s, 8);
      u64 key = ((u64)__float_as_uint(s) << 32) | (unsigned)codeg;
      u64 ok = __shfl_xor(key, 16);
      key = umin64(key, ok);
      ok = __shfl_xor(key, 32);
      key = umin64(key, ok);
      k[r] = key;
    }

    if (lane == 0) {
      int rows[8];
      u64 cur[8];
#pragma unroll
      for (int r = 0; r < 8; ++r) rows[r] = rl[buf][r];
#pragma unroll
      for (int r = 0; r < 8; ++r) cur[r] = bestkey[rows[r]];
#pragma unroll
      for (int r = 0; r < 8; ++r)
        if (k[r] < cur[r]) atomicMin(&bestkey[rows[r]], k[r]);
    }
  }
}

// ---------------------------------------------------------------------------
// K5: gather quantized output + per-block loss partials (no global atomics).
// ---------------------------------------------------------------------------
__launch_bounds__(256)
__global__ void k_out2(const float* __restrict__ x, const float* __restrict__ cb,
                       const unsigned* __restrict__ bestidx,
                       const u64* __restrict__ bestkey,
                       float* __restrict__ out, float* __restrict__ partials) {
  __shared__ float wsum[4];
  float s = 0.f;
#pragma unroll
  for (int it = 0; it < 4; ++it) {
    const int gid = (it * 2048 + blockIdx.x) * 256 + threadIdx.x;
    const int row = gid >> 6, d4 = gid & 63;
    const unsigned bi = bestidx[row];
    unsigned idx = bi & 0x7fffffffu;
    if (bi >> 31) idx = (unsigned)(bestkey[row] & 0xffffffffull);
    const float4 q = *(const float4*)(cb + (size_t)idx * DIMS + d4 * 4);
    const float4 xv = *(const float4*)(x + (size_t)gid * 4);
    *(float4*)(out + (size_t)gid * 4) = q;
    const float dx = q.x - xv.x, dy = q.y - xv.y, dz = q.z - xv.z, dw = q.w - xv.w;
    s += dx * dx + dy * dy + dz * dz + dw * dw;
  }
#pragma unroll
  for (int m = 1; m < 64; m <<= 1) s += __shfl_xor(s, m);
  if ((threadIdx.x & 63) == 0) wsum[threadIdx.x >> 6] = s;
  __syncthreads();
  if (threadIdx.x == 0)
    partials[blockIdx.x] = wsum[0] + wsum[1] + wsum[2] + wsum[3];
}

// ---------------------------------------------------------------------------
// K6: final loss reduce.
// ---------------------------------------------------------------------------
__global__ void k_loss(const float* __restrict__ partials, float* __restrict__ loss_cell) {
  __shared__ double wsum[4];
  double s = 0.0;
#pragma unroll
  for (int i = 0; i < 8; ++i) s += (double)partials[i * 256 + threadIdx.x];
#pragma unroll
  for (int m = 1; m < 64; m <<= 1) s += __shfl_xor(s, m);
  if ((threadIdx.x & 63) == 0) wsum[threadIdx.x >> 6] = s;
  __syncthreads();
  if (threadIdx.x == 0)
    *loss_cell = (float)((wsum[0] + wsum[1] + wsum[2] + wsum[3]) *
                         (1.25 / (double)((size_t)NROWS * DIMS)));
}

// ---------------------------------------------------------------------------
extern "C" void kernel_launch(void* const* d_in, const int* in_sizes, int n_in,
                              void* d_out, int out_size, void* d_ws, size_t ws_size,
                              hipStream_t stream) {
  const float* x = (const float*)d_in[0];
  const float* cb = (const float*)d_in[1];
  float* out = (float*)d_out;
  char* ws = (char*)d_ws;

  float* cnorm = (float*)(ws + 0);            //  32 KB
  u64* pk1 = (u64*)(ws + 32768);              // 512 KB
  u64* pk2 = (u64*)(ws + 557056);             // 512 KB
  float* d3h = (float*)(ws + 1081344);        // 256 KB
  unsigned* bestidx = (unsigned*)(ws + 1343488);  // 128 KB
  u64* bestkey = (u64*)(ws + 1474560);        // 256 KB
  int* wlist = (int*)(ws + 1736704);          // 128 KB
  int* slist = (int*)(ws + 1867776);          // 128 KB
  int* wcount = (int*)(ws + 1998848);
  int* scount = wcount + 1;
  float* partials = (float*)(ws + 1998912);   //   8 KB
  _Float16* cbh = (_Float16*)(ws + 2007104);  //   4 MB (fast path)
  float* loss_cell = out + (NROWS * DIMS);

  const bool fast = ws_size >= (size_t)(2007104 + KCODES * DIMS * 2);

  k_cnorm<<<KCODES / 4, 256, 0, stream>>>(cb, cnorm, wcount, scount, loss_cell);
  if (fast) {
    k_prep<<<KCODES * DIMS / 8 / 256, 256, 0, stream>>>(cb, cbh);
    k_gemm2<<<256, 512, 0, stream>>>(x, cbh, cnorm, pk1, pk2, d3h);
  } else {
    k_gemm<<<256, 512, 0, stream>>>(x, cb, cnorm, pk1, pk2, d3h);
  }
  k_merge<<<NROWS / 256, 256, 0, stream>>>(pk1, pk2, d3h, bestidx, bestkey,
                                           wlist, wcount, slist, scount);
  k_soft<<<64, 256, 0, stream>>>(x, cb, pk1, pk2, slist, scount, bestidx);
  k_refine3<<<KCODES / 32, 512, 0, stream>>>(x, cb, wlist, wcount, bestkey);
  k_out2<<<2048, 256, 0, stream>>>(x, cb, bestidx, bestkey, out, partials);
  k_loss<<<1, 256, 0, stream>>>(partials, loss_cell);
}